// Round 10
// baseline (497.640 us; speedup 1.0000x reference)
//
#include <hip/hip_runtime.h>
#include <cfloat>
#include <cstdint>

#define B_   8
#define N_   1024
#define H_   128
#define K_   20
#define EPS_ 1e-6f
#define R_   (B_ * 3 * N_)

typedef _Float16 half_t;
typedef _Float16 h8_t __attribute__((ext_vector_type(8)));
typedef _Float16 h4_t __attribute__((ext_vector_type(4)));
typedef __attribute__((ext_vector_type(4))) float f4_t;
typedef unsigned long long ull;

__device__ inline f4_t ld4h(const half_t* __restrict__ p, size_t off) {
    h4_t x = *(const h4_t*)(p + off);
    f4_t r;
    r[0] = (float)x[0]; r[1] = (float)x[1]; r[2] = (float)x[2]; r[3] = (float)x[3];
    return r;
}
__device__ inline void st4h(half_t* __restrict__ p, size_t off, f4_t v) {
    h4_t o;
    o[0] = (half_t)v[0]; o[1] = (half_t)v[1]; o[2] = (half_t)v[2]; o[3] = (half_t)v[3];
    *(h4_t*)(p + off) = o;
}

// ---------------------------------------------------------------------------
// All-weights fp32 -> fp16 hi + fp16 lo split.
// ---------------------------------------------------------------------------
#define OFF_FC 0
#define OFF_D0 32768
#define OFF_W0 294912
#define OFF_D1 425984
#define OFF_W1 491520
#define OFF_WS 557056
#define W_TOT  688128
__global__ __launch_bounds__(256) void cvt_all(const float* __restrict__ Wfc,
                                               const float* __restrict__ Wd0,
                                               const float* __restrict__ W0,
                                               const float* __restrict__ Wd1,
                                               const float* __restrict__ W1,
                                               const float* __restrict__ Wsc,
                                               half_t* __restrict__ hi,
                                               half_t* __restrict__ lo) {
    int i = blockIdx.x * 256 + threadIdx.x;
    if (i >= W_TOT) return;
    const float* src; int off;
    if (i < OFF_W0)      { if (i < OFF_D0) { src = Wfc; off = OFF_FC; }
                           else            { src = Wd0; off = OFF_D0; } }
    else if (i < OFF_W1) { if (i < OFF_D1) { src = W0;  off = OFF_W0; }
                           else            { src = Wd1; off = OFF_D1; } }
    else                 { if (i < OFF_WS) { src = W1;  off = OFF_W1; }
                           else            { src = Wsc; off = OFF_WS; } }
    float w = src[i - off];
    half_t h = (half_t)w;
    half_t l = (half_t)(w - (float)h);
    hi[i] = h; lo[i] = l;
}

// ---------------------------------------------------------------------------
// kNN: LDS point cloud + 20 rounds of packed (dist,idx) u64 xor-butterfly
// min. No ballot, no masked rescan. Block = 4 queries (one per wave).
// ---------------------------------------------------------------------------
__global__ __launch_bounds__(256) void knn_wave(const float* __restrict__ x,
                                                int* __restrict__ idx) {
    __shared__ float xs[N_], ys[N_], zs[N_];
    int t = threadIdx.x;
    int wv = t >> 6, lane = t & 63;
    int b = blockIdx.x >> 8;
    int n = (blockIdx.x & 255) * 4 + wv;
    const float* xb = x + (size_t)b * N_ * 3;
    for (int j = t; j < N_; j += 256) {
        xs[j] = xb[j * 3 + 0];
        ys[j] = xb[j * 3 + 1];
        zs[j] = xb[j * 3 + 2];
    }
    __syncthreads();

    float cx = xs[n], cy = ys[n], cz = zs[n];
    ull ku[16];
    #pragma unroll
    for (int k = 0; k < 16; ++k) {
        int j = lane + (k << 6);
        float dx = xs[j] - cx, dy = ys[j] - cy, dz = zs[j] - cz;
        float d = dx * dx + dy * dy + dz * dz;
        ku[k] = ((ull)__float_as_uint(d) << 32) | (uint)j;
    }

    int* op = idx + (size_t)(b * N_ + n) * K_;
    for (int s = 0; s < K_; ++s) {
        ull m = ku[0];
        #pragma unroll
        for (int k = 1; k < 16; ++k) m = (ku[k] < m) ? ku[k] : m;
        #pragma unroll
        for (int o = 32; o; o >>= 1) {
            ull om = __shfl_xor(m, o);
            m = (om < m) ? om : m;
        }
        int j = (int)(uint)m;
        if ((j & 63) == lane) {
            op[s] = j;
            ku[j >> 6] = ~0ull;
        }
    }
}

// ---------------------------------------------------------------------------
// conv_pos fused -> h1 fp16 plane (B,3,N,128).
// ---------------------------------------------------------------------------
__global__ __launch_bounds__(128) void convpos_kernel(const float* __restrict__ x,
                                                      const int* __restrict__ idx,
                                                      const float* __restrict__ Wf,
                                                      const float* __restrict__ Wd,
                                                      half_t* __restrict__ h1) {
    int bn = blockIdx.x;
    int b = bn >> 10, n = bn & 1023;
    const float* xb = x + (size_t)b * N_ * 3;

    __shared__ float nb[K_][3];
    __shared__ float ctr[3];
    int t = threadIdx.x;
    if (t < K_) {
        int j = idx[(size_t)bn * K_ + t];
        nb[t][0] = xb[j * 3 + 0];
        nb[t][1] = xb[j * 3 + 1];
        nb[t][2] = xb[j * 3 + 2];
    }
    if (t == K_) {
        ctr[0] = xb[n * 3 + 0]; ctr[1] = xb[n * 3 + 1]; ctr[2] = xb[n * 3 + 2];
    }
    __syncthreads();

    float cx = ctr[0], cy = ctr[1], cz = ctr[2];
    float wf0 = Wf[t * 3 + 0], wf1 = Wf[t * 3 + 1], wf2 = Wf[t * 3 + 2];
    float wd0 = Wd[t * 3 + 0], wd1 = Wd[t * 3 + 1], wd2 = Wd[t * 3 + 2];

    float ax = 0.f, ay = 0.f, az = 0.f;
    #pragma unroll 4
    for (int kk = 0; kk < K_; ++kk) {
        float nx = nb[kk][0], ny = nb[kk][1], nz = nb[kk][2];
        float ex = nx - cx, ey = ny - cy, ez = nz - cz;
        float rx = ny * cz - nz * cy;
        float ry = nz * cx - nx * cz;
        float rz = nx * cy - ny * cx;
        float fx = wf0 * ex + wf1 * cx + wf2 * rx;
        float fy = wf0 * ey + wf1 * cy + wf2 * ry;
        float fz = wf0 * ez + wf1 * cz + wf2 * rz;
        float gx = wd0 * ex + wd1 * cx + wd2 * rx;
        float gy = wd0 * ey + wd1 * cy + wd2 * ry;
        float gz = wd0 * ez + wd1 * cz + wd2 * rz;
        float dot = fx * gx + fy * gy + fz * gz;
        float dsq = gx * gx + gy * gy + gz * gz + EPS_;
        float coef = dot / dsq;
        float qx, qy, qz;
        if (dot >= 0.f) { qx = fx; qy = fy; qz = fz; }
        else            { qx = fx - coef * gx; qy = fy - coef * gy; qz = fz - coef * gz; }
        ax += 0.2f * fx + 0.8f * qx;
        ay += 0.2f * fy + 0.8f * qy;
        az += 0.2f * fz + 0.8f * qz;
    }
    const float inv = 1.0f / (float)K_;
    size_t r0 = ((size_t)b * 3) * N_ + n;
    h1[(r0) * H_ + t]          = (half_t)(ax * inv);
    h1[(r0 + N_) * H_ + t]     = (half_t)(ay * inv);
    h1[(r0 + 2 * N_) * H_ + t] = (half_t)(az * inv);
}

// ---------------------------------------------------------------------------
// Direct-register 3-v GEMM: NO LDS, NO barriers. One wave computes a
// 32(m) x 16(n) x 3(v) tile; fragments loaded straight from global
// (one dwordx4 per lane per fragment; weights L1/L2-resident).
// CT = K (compile-time, fully unrolled). RELU_MODE: 0=none, 1=VN-relu
// p from pA (stride O), 2=VN-relu p=[pA (o<128, stride 128) | P bcast].
// ---------------------------------------------------------------------------
template<int CT, int RELU_MODE, bool HAS_ROWADD>
__global__ __launch_bounds__(256) void gemm3v(const half_t* __restrict__ Whi,
                                              const half_t* __restrict__ Wlo,
                                              int lda,
                                              const half_t* __restrict__ A,
                                              const half_t* __restrict__ pA,
                                              const float* __restrict__ P,
                                              const float* __restrict__ rowAdd,
                                              half_t* __restrict__ outA,
                                              int O) {
    const int t = threadIdx.x;
    const int lane = t & 63, wave = t >> 6;
    const int l16 = lane & 15, quad = lane >> 4;
    const int m0 = blockIdx.y * 32;
    const int b  = blockIdx.z;
    const int n0 = (blockIdx.x * 4 + wave) * 16;

    f4_t acc[3][2];
    #pragma unroll
    for (int v = 0; v < 3; ++v)
        #pragma unroll
        for (int i = 0; i < 2; ++i)
            #pragma unroll
            for (int e = 0; e < 4; ++e) acc[v][i][e] = 0.f;

    const half_t* wh0 = Whi + (size_t)(m0 + l16) * lda + quad * 8;
    const half_t* wl0 = Wlo + (size_t)(m0 + l16) * lda + quad * 8;
    const half_t* bp[3];
    #pragma unroll
    for (int v = 0; v < 3; ++v)
        bp[v] = A + (size_t)((b * 3 + v) * N_ + n0 + l16) * CT + quad * 8;

    #pragma unroll
    for (int k0 = 0; k0 < CT; k0 += 32) {
        h8_t ah0 = *(const h8_t*)(wh0 + k0);
        h8_t ah1 = *(const h8_t*)(wh0 + (size_t)16 * lda + k0);
        h8_t al0 = *(const h8_t*)(wl0 + k0);
        h8_t al1 = *(const h8_t*)(wl0 + (size_t)16 * lda + k0);
        h8_t bh[3];
        #pragma unroll
        for (int v = 0; v < 3; ++v) bh[v] = *(const h8_t*)(bp[v] + k0);
        #pragma unroll
        for (int v = 0; v < 3; ++v) {
            acc[v][0] = __builtin_amdgcn_mfma_f32_16x16x32_f16(ah0, bh[v], acc[v][0], 0, 0, 0);
            acc[v][0] = __builtin_amdgcn_mfma_f32_16x16x32_f16(al0, bh[v], acc[v][0], 0, 0, 0);
            acc[v][1] = __builtin_amdgcn_mfma_f32_16x16x32_f16(ah1, bh[v], acc[v][1], 0, 0, 0);
            acc[v][1] = __builtin_amdgcn_mfma_f32_16x16x32_f16(al1, bh[v], acc[v][1], 0, 0, 0);
        }
    }

    const int n = n0 + l16;
    const size_t row0 = (size_t)(b * 3) * N_ + n;
    #pragma unroll
    for (int i = 0; i < 2; ++i) {
        int o = m0 + i * 16 + quad * 4;
        f4_t d[3];
        #pragma unroll
        for (int v = 0; v < 3; ++v) {
            d[v] = acc[v][i];
            if (HAS_ROWADD) {
                float4 ra = *(const float4*)(rowAdd + (size_t)(b * 3 + v) * O + o);
                d[v][0] += ra.x; d[v][1] += ra.y; d[v][2] += ra.z; d[v][3] += ra.w;
            }
        }
        if (RELU_MODE == 0) {
            #pragma unroll
            for (int v = 0; v < 3; ++v)
                st4h(outA, (row0 + (size_t)v * N_) * O + o, d[v]);
        } else {
            f4_t p[3];
            if (RELU_MODE == 1) {
                #pragma unroll
                for (int v = 0; v < 3; ++v)
                    p[v] = ld4h(pA, (row0 + (size_t)v * N_) * O + o);
            } else {
                if (o < 128) {
                    #pragma unroll
                    for (int v = 0; v < 3; ++v)
                        p[v] = ld4h(pA, (row0 + (size_t)v * N_) * 128 + o);
                } else {
                    #pragma unroll
                    for (int e = 0; e < 4; ++e) {
                        const float* Pc = P + (size_t)(b * 128 + o - 128 + e) * 3;
                        p[0][e] = Pc[0]; p[1][e] = Pc[1]; p[2][e] = Pc[2];
                    }
                }
            }
            f4_t q[3];
            #pragma unroll
            for (int e = 0; e < 4; ++e) {
                float dot = p[0][e] * d[0][e] + p[1][e] * d[1][e] + p[2][e] * d[2][e];
                float dsq = d[0][e] * d[0][e] + d[1][e] * d[1][e] + d[2][e] * d[2][e] + EPS_;
                float cf = dot / dsq;
                if (dot >= 0.f) { q[0][e] = p[0][e]; q[1][e] = p[1][e]; q[2][e] = p[2][e]; }
                else {
                    q[0][e] = p[0][e] - cf * d[0][e];
                    q[1][e] = p[1][e] - cf * d[1][e];
                    q[2][e] = p[2][e] - cf * d[2][e];
                }
            }
            #pragma unroll
            for (int v = 0; v < 3; ++v)
                st4h(outA, (row0 + (size_t)v * N_) * O + o, q[v]);
        }
    }
}

// ---------------------------------------------------------------------------
// Direct-register dual-segment GEMM (h = Ws*hidden + W1*a1 + rowAdd), fused
// pool partials, optional h write. O=128, wave tile 32x16x3v.
// Pp layout: [(b*64 + ntile) * 384 + o*3 + v]
// ---------------------------------------------------------------------------
template<int C0T, int C1T, bool HAS_ROWADD, bool WRITE_OUT>
__global__ __launch_bounds__(256) void gemm3v_dual(const half_t* __restrict__ W0h,
                                                   const half_t* __restrict__ W0l,
                                                   int lda0,
                                                   const half_t* __restrict__ A0,
                                                   const half_t* __restrict__ W1h,
                                                   const half_t* __restrict__ W1l,
                                                   int lda1,
                                                   const half_t* __restrict__ A1,
                                                   const float* __restrict__ rowAdd,
                                                   half_t* __restrict__ outA,
                                                   float* __restrict__ Pp) {
    constexpr int O = 128;
    const int t = threadIdx.x;
    const int lane = t & 63, wave = t >> 6;
    const int l16 = lane & 15, quad = lane >> 4;
    const int m0 = blockIdx.y * 32;
    const int b  = blockIdx.z;
    const int nt = blockIdx.x * 4 + wave;
    const int n0 = nt * 16;

    f4_t acc[3][2];
    #pragma unroll
    for (int v = 0; v < 3; ++v)
        #pragma unroll
        for (int i = 0; i < 2; ++i)
            #pragma unroll
            for (int e = 0; e < 4; ++e) acc[v][i][e] = 0.f;

    {   // segment 0
        const half_t* wh0 = W0h + (size_t)(m0 + l16) * lda0 + quad * 8;
        const half_t* wl0 = W0l + (size_t)(m0 + l16) * lda0 + quad * 8;
        const half_t* bp[3];
        #pragma unroll
        for (int v = 0; v < 3; ++v)
            bp[v] = A0 + (size_t)((b * 3 + v) * N_ + n0 + l16) * C0T + quad * 8;
        #pragma unroll
        for (int k0 = 0; k0 < C0T; k0 += 32) {
            h8_t ah0 = *(const h8_t*)(wh0 + k0);
            h8_t ah1 = *(const h8_t*)(wh0 + (size_t)16 * lda0 + k0);
            h8_t al0 = *(const h8_t*)(wl0 + k0);
            h8_t al1 = *(const h8_t*)(wl0 + (size_t)16 * lda0 + k0);
            h8_t bh[3];
            #pragma unroll
            for (int v = 0; v < 3; ++v) bh[v] = *(const h8_t*)(bp[v] + k0);
            #pragma unroll
            for (int v = 0; v < 3; ++v) {
                acc[v][0] = __builtin_amdgcn_mfma_f32_16x16x32_f16(ah0, bh[v], acc[v][0], 0, 0, 0);
                acc[v][0] = __builtin_amdgcn_mfma_f32_16x16x32_f16(al0, bh[v], acc[v][0], 0, 0, 0);
                acc[v][1] = __builtin_amdgcn_mfma_f32_16x16x32_f16(ah1, bh[v], acc[v][1], 0, 0, 0);
                acc[v][1] = __builtin_amdgcn_mfma_f32_16x16x32_f16(al1, bh[v], acc[v][1], 0, 0, 0);
            }
        }
    }
    {   // segment 1
        const half_t* wh0 = W1h + (size_t)(m0 + l16) * lda1 + quad * 8;
        const half_t* wl0 = W1l + (size_t)(m0 + l16) * lda1 + quad * 8;
        const half_t* bp[3];
        #pragma unroll
        for (int v = 0; v < 3; ++v)
            bp[v] = A1 + (size_t)((b * 3 + v) * N_ + n0 + l16) * C1T + quad * 8;
        #pragma unroll
        for (int k0 = 0; k0 < C1T; k0 += 32) {
            h8_t ah0 = *(const h8_t*)(wh0 + k0);
            h8_t ah1 = *(const h8_t*)(wh0 + (size_t)16 * lda1 + k0);
            h8_t al0 = *(const h8_t*)(wl0 + k0);
            h8_t al1 = *(const h8_t*)(wl0 + (size_t)16 * lda1 + k0);
            h8_t bh[3];
            #pragma unroll
            for (int v = 0; v < 3; ++v) bh[v] = *(const h8_t*)(bp[v] + k0);
            #pragma unroll
            for (int v = 0; v < 3; ++v) {
                acc[v][0] = __builtin_amdgcn_mfma_f32_16x16x32_f16(ah0, bh[v], acc[v][0], 0, 0, 0);
                acc[v][0] = __builtin_amdgcn_mfma_f32_16x16x32_f16(al0, bh[v], acc[v][0], 0, 0, 0);
                acc[v][1] = __builtin_amdgcn_mfma_f32_16x16x32_f16(ah1, bh[v], acc[v][1], 0, 0, 0);
                acc[v][1] = __builtin_amdgcn_mfma_f32_16x16x32_f16(al1, bh[v], acc[v][1], 0, 0, 0);
            }
        }
    }

    const int n = n0 + l16;
    const size_t row0 = (size_t)(b * 3) * N_ + n;
    const size_t slot = (size_t)b * 64 + nt;
    #pragma unroll
    for (int i = 0; i < 2; ++i) {
        int o = m0 + i * 16 + quad * 4;
        f4_t d[3];
        #pragma unroll
        for (int v = 0; v < 3; ++v) {
            d[v] = acc[v][i];
            if (HAS_ROWADD) {
                float4 ra = *(const float4*)(rowAdd + (size_t)(b * 3 + v) * O + o);
                d[v][0] += ra.x; d[v][1] += ra.y; d[v][2] += ra.z; d[v][3] += ra.w;
            }
            if (WRITE_OUT)
                st4h(outA, (row0 + (size_t)v * N_) * O + o, d[v]);
        }
        // reduce over 16-lane n-group
        #pragma unroll
        for (int v = 0; v < 3; ++v)
            #pragma unroll
            for (int e = 0; e < 4; ++e) {
                float s = d[v][e];
                s += __shfl_xor(s, 1);
                s += __shfl_xor(s, 2);
                s += __shfl_xor(s, 4);
                s += __shfl_xor(s, 8);
                d[v][e] = s;
            }
        if (l16 == 0) {
            #pragma unroll
            for (int v = 0; v < 3; ++v)
                #pragma unroll
                for (int e = 0; e < 4; ++e)
                    Pp[slot * 384 + (size_t)(o + e) * 3 + v] = d[v][e];
        }
    }
}

// ---------------------------------------------------------------------------
// Exact pooled-half injection (fp32 original weights + fp32 P).
// ---------------------------------------------------------------------------
__global__ __launch_bounds__(256) void rowadd_kernel(const float* __restrict__ Wd0i,
                                                     const float* __restrict__ Wsi,
                                                     const float* __restrict__ P,
                                                     float* __restrict__ addD0,
                                                     float* __restrict__ addWs) {
    int s = blockIdx.x;               // b*3 + v
    int b = s / 3, v = s % 3;
    __shared__ float Pl[128];
    int t = threadIdx.x;
    if (t < 128) Pl[t] = P[(size_t)(b * 128 + t) * 3 + v];
    __syncthreads();
    float sum = 0.f;
    const float* wr = Wd0i + (size_t)t * 256 + 128;
    #pragma unroll 8
    for (int c = 0; c < 128; ++c) sum += wr[c] * Pl[c];
    addD0[(size_t)s * 256 + t] = sum;
    if (t < 128) {
        const float* wr2 = Wsi + (size_t)t * 256 + 128;
        float s2 = 0.f;
        #pragma unroll 8
        for (int c = 0; c < 128; ++c) s2 += wr2[c] * Pl[c];
        addWs[(size_t)s * 128 + t] = s2;
    }
}

// ---------------------------------------------------------------------------
// Pool stage 2: reduce 64 partial slots -> P (B,128,3), scaled by 1/N.
// ---------------------------------------------------------------------------
__global__ __launch_bounds__(128) void pool2_kernel(const float* __restrict__ Pp,
                                                    float* __restrict__ P) {
    int b = blockIdx.x;
    int c = threadIdx.x;
    float s0 = 0.f, s1 = 0.f, s2 = 0.f;
    for (int sl = 0; sl < 64; ++sl) {
        const float* p = Pp + ((size_t)b * 64 + sl) * 384 + (size_t)c * 3;
        s0 += p[0]; s1 += p[1]; s2 += p[2];
    }
    float* o = P + (size_t)(b * 128 + c) * 3;
    const float inv = 1.0f / (float)N_;
    o[0] = s0 * inv; o[1] = s1 * inv; o[2] = s2 * inv;
}

// ---------------------------------------------------------------------------
// Final stage (fp32, exact)
// ---------------------------------------------------------------------------
__global__ __launch_bounds__(128) void final_kernel(const float* __restrict__ P,
                                                    const float* __restrict__ Wd,
                                                    const float* __restrict__ Wc,
                                                    float* __restrict__ out) {
    int b = blockIdx.x;
    int t = threadIdx.x;
    __shared__ float hid[H_][3];
    __shared__ float act[H_][3];
    const float* Pb = P + (size_t)b * H_ * 3;
    hid[t][0] = Pb[t * 3 + 0];
    hid[t][1] = Pb[t * 3 + 1];
    hid[t][2] = Pb[t * 3 + 2];
    __syncthreads();

    float d0 = 0.f, d1 = 0.f, d2 = 0.f;
    const float* wd = Wd + (size_t)t * H_;
    for (int c = 0; c < H_; ++c) {
        float w = wd[c];
        d0 += w * hid[c][0]; d1 += w * hid[c][1]; d2 += w * hid[c][2];
    }
    float p0 = hid[t][0], p1 = hid[t][1], p2 = hid[t][2];
    float dot = p0 * d0 + p1 * d1 + p2 * d2;
    float dsq = d0 * d0 + d1 * d1 + d2 * d2 + EPS_;
    float cf = dot / dsq;
    float q0, q1, q2;
    if (dot >= 0.f) { q0 = p0; q1 = p1; q2 = p2; }
    else            { q0 = p0 - cf * d0; q1 = p1 - cf * d1; q2 = p2 - cf * d2; }
    act[t][0] = 0.2f * p0 + 0.8f * q0;
    act[t][1] = 0.2f * p1 + 0.8f * q1;
    act[t][2] = 0.2f * p2 + 0.8f * q2;
    __syncthreads();

    float o0 = 0.f, o1 = 0.f, o2 = 0.f;
    const float* wc = Wc + (size_t)t * H_;
    for (int c = 0; c < H_; ++c) {
        float w = wc[c];
        o0 += w * act[c][0]; o1 += w * act[c][1]; o2 += w * act[c][2];
    }
    size_t ob = ((size_t)b * H_ + t) * 3;
    out[ob + 0] = o0; out[ob + 1] = o1; out[ob + 2] = o2;
}

// ---------------------------------------------------------------------------
extern "C" void kernel_launch(void* const* d_in, const int* in_sizes, int n_in,
                              void* d_out, int out_size, void* d_ws, size_t ws_size,
                              hipStream_t stream) {
    const float* x   = (const float*)d_in[0];
    const float* Wf  = (const float*)d_in[1];
    const float* Wdp = (const float*)d_in[2];
    const float* Wfc = (const float*)d_in[3];
    const float* Wd0 = (const float*)d_in[4];
    const float* W0  = (const float*)d_in[5];
    const float* Wd1 = (const float*)d_in[6];
    const float* W1  = (const float*)d_in[7];
    const float* Wsc = (const float*)d_in[8];
    const float* Wda = (const float*)d_in[9];
    const float* Wc  = (const float*)d_in[10];
    float* out = (float*)d_out;
    (void)in_sizes; (void)n_in; (void)out_size; (void)ws_size;

    char* ws = (char*)d_ws;
    size_t off = 0;
    auto alloc = [&](size_t bytes) {
        void* p = ws + off;
        off = (off + bytes + 255) & ~(size_t)255;
        return p;
    };
    const size_t e128 = (size_t)R_ * 128;
    const size_t e256 = (size_t)R_ * 256;
    int*    idx   = (int*)   alloc((size_t)B_ * N_ * K_ * sizeof(int));
    half_t* wAllH = (half_t*)alloc((size_t)W_TOT * 2);
    half_t* wAllL = (half_t*)alloc((size_t)W_TOT * 2);
    half_t* h1F   = (half_t*)alloc(e128 * 2);
    half_t* HdF   = (half_t*)alloc(e256 * 2);
    half_t* a0F   = (half_t*)alloc(e256 * 2);
    half_t* netF  = (half_t*)alloc(e128 * 2);
    half_t* a1F   = (half_t*)alloc(e128 * 2);
    half_t* hF[2] = { (half_t*)alloc(e128 * 2), (half_t*)alloc(e128 * 2) };
    float*  addD0 = (float*) alloc(24 * 256 * 4);
    float*  addWs = (float*) alloc(24 * 128 * 4);
    float*  Pp    = (float*) alloc((size_t)B_ * 64 * 384 * 4);
    float*  P     = (float*) alloc((size_t)B_ * 128 * 3 * 4);

    const half_t* whFc = wAllH + OFF_FC; const half_t* wlFc = wAllL + OFF_FC;
    const half_t* whD0 = wAllH + OFF_D0; const half_t* wlD0 = wAllL + OFF_D0;
    const half_t* whW0 = wAllH + OFF_W0; const half_t* wlW0 = wAllL + OFF_W0;
    const half_t* whD1 = wAllH + OFF_D1; const half_t* wlD1 = wAllL + OFF_D1;
    const half_t* whW1 = wAllH + OFF_W1; const half_t* wlW1 = wAllL + OFF_W1;
    const half_t* whWs = wAllH + OFF_WS; const half_t* wlWs = wAllL + OFF_WS;

    hipLaunchKernelGGL(cvt_all, dim3((W_TOT + 255) / 256), dim3(256), 0, stream,
                       Wfc, Wd0, W0, Wd1, W1, Wsc, wAllH, wAllL);
    hipLaunchKernelGGL(knn_wave, dim3(B_ * N_ / 4), dim3(256), 0, stream, x, idx);
    hipLaunchKernelGGL(convpos_kernel, dim3(B_ * N_), dim3(128), 0, stream,
                       x, idx, Wf, Wdp, h1F);

    // fc_pos: Hd = Wfc (256x128) * h1
    gemm3v<128, 0, false><<<dim3(16, 8, 8), 256, 0, stream>>>(
        whFc, wlFc, 128, h1F, nullptr, nullptr, nullptr, HdF, 256);

    for (int i = 0; i < 4; ++i) {
        int cur = i & 1, prv = cur ^ 1;
        if (i == 0) {
            // a0 = vnrelu(Hd, Wd0*Hd)
            gemm3v<256, 1, false><<<dim3(16, 8, 8), 256, 0, stream>>>(
                whD0, wlD0, 256, HdF, HdF, nullptr, nullptr, a0F, 256);
        } else {
            hipLaunchKernelGGL(rowadd_kernel, dim3(24), dim3(256), 0, stream,
                               Wd0 + (size_t)i * 65536, Wsc + (size_t)i * 32768,
                               P, addD0, addWs);
            // a0 = vnrelu([h|P], Wd0_left*h + rowAdd)
            gemm3v<128, 2, true><<<dim3(16, 8, 8), 256, 0, stream>>>(
                whD0 + (size_t)i * 65536, wlD0 + (size_t)i * 65536, 256,
                hF[prv], hF[prv], P, addD0, a0F, 256);
        }
        // net = W0 * a0
        gemm3v<256, 0, false><<<dim3(16, 4, 8), 256, 0, stream>>>(
            whW0 + (size_t)i * 32768, wlW0 + (size_t)i * 32768, 256,
            a0F, nullptr, nullptr, nullptr, netF, 128);
        // a1 = vnrelu(net, Wd1*net)
        gemm3v<128, 1, false><<<dim3(16, 4, 8), 256, 0, stream>>>(
            whD1 + (size_t)i * 16384, wlD1 + (size_t)i * 16384, 128,
            netF, netF, nullptr, nullptr, a1F, 128);
        // h = [Ws | W1] * [hidden ; a1] (+rowAdd) ; fused pool partials
        if (i == 0) {
            gemm3v_dual<256, 128, false, true><<<dim3(16, 4, 8), 256, 0, stream>>>(
                whWs, wlWs, 256, HdF,
                whW1, wlW1, 128, a1F,
                nullptr, hF[cur], Pp);
        } else if (i < 3) {
            gemm3v_dual<128, 128, true, true><<<dim3(16, 4, 8), 256, 0, stream>>>(
                whWs + (size_t)i * 32768, wlWs + (size_t)i * 32768, 256, hF[prv],
                whW1 + (size_t)i * 16384, wlW1 + (size_t)i * 16384, 128, a1F,
                addWs, hF[cur], Pp);
        } else {
            gemm3v_dual<128, 128, true, false><<<dim3(16, 4, 8), 256, 0, stream>>>(
                whWs + (size_t)i * 32768, wlWs + (size_t)i * 32768, 256, hF[prv],
                whW1 + (size_t)i * 16384, wlW1 + (size_t)i * 16384, 128, a1F,
                addWs, nullptr, Pp);
        }
        hipLaunchKernelGGL(pool2_kernel, dim3(B_), dim3(128), 0, stream, Pp, P);
    }

    hipLaunchKernelGGL(final_kernel, dim3(B_), dim3(128), 0, stream, P, Wda, Wc, out);
}

// Round 11
// 365.568 us; speedup vs baseline: 1.3613x; 1.3613x over previous
//
#include <hip/hip_runtime.h>
#include <cfloat>
#include <cstdint>

#define B_   8
#define N_   1024
#define H_   128
#define K_   20
#define EPS_ 1e-6f
#define R_   (B_ * 3 * N_)

typedef _Float16 half_t;
typedef _Float16 h8_t __attribute__((ext_vector_type(8)));
typedef _Float16 h4_t __attribute__((ext_vector_type(4)));
typedef __attribute__((ext_vector_type(4))) float f4_t;

__device__ inline f4_t ld4h(const half_t* __restrict__ p, size_t off) {
    h4_t x = *(const h4_t*)(p + off);
    f4_t r;
    r[0] = (float)x[0]; r[1] = (float)x[1]; r[2] = (float)x[2]; r[3] = (float)x[3];
    return r;
}
__device__ inline void st4h(half_t* __restrict__ p, size_t off, f4_t v) {
    h4_t o;
    o[0] = (half_t)v[0]; o[1] = (half_t)v[1]; o[2] = (half_t)v[2]; o[3] = (half_t)v[3];
    *(h4_t*)(p + off) = o;
}

// ---------------------------------------------------------------------------
// All-weights fp32 -> fp16 (single plane; weight rounding ~2^-12 rel,
// contributes ~0.15e-3 to final absmax per R2/R3 error accounting).
// ---------------------------------------------------------------------------
#define OFF_FC 0
#define OFF_D0 32768
#define OFF_W0 294912
#define OFF_D1 425984
#define OFF_W1 491520
#define OFF_WS 557056
#define W_TOT  688128
__global__ __launch_bounds__(256) void cvt_all(const float* __restrict__ Wfc,
                                               const float* __restrict__ Wd0,
                                               const float* __restrict__ W0,
                                               const float* __restrict__ Wd1,
                                               const float* __restrict__ W1,
                                               const float* __restrict__ Wsc,
                                               half_t* __restrict__ w) {
    int i = blockIdx.x * 256 + threadIdx.x;
    if (i >= W_TOT) return;
    const float* src; int off;
    if (i < OFF_W0)      { if (i < OFF_D0) { src = Wfc; off = OFF_FC; }
                           else            { src = Wd0; off = OFF_D0; } }
    else if (i < OFF_W1) { if (i < OFF_D1) { src = W0;  off = OFF_W0; }
                           else            { src = Wd1; off = OFF_D1; } }
    else                 { if (i < OFF_WS) { src = W1;  off = OFF_W1; }
                           else            { src = Wsc; off = OFF_WS; } }
    w[i] = (half_t)src[i - off];
}

// ---------------------------------------------------------------------------
// kNN: LDS cloud + 20 rounds of packed-u32 (dist-hi22 | idx10) butterfly min.
// Selection is exact up to 2^-13-relative distance ties (output depends on
// per-point features only through means over N; negligible).
// ---------------------------------------------------------------------------
__global__ __launch_bounds__(256) void knn_wave(const float* __restrict__ x,
                                                int* __restrict__ idx) {
    __shared__ float xs[N_], ys[N_], zs[N_];
    int t = threadIdx.x;
    int wv = t >> 6, lane = t & 63;
    int b = blockIdx.x >> 8;
    int n = (blockIdx.x & 255) * 4 + wv;
    const float* xb = x + (size_t)b * N_ * 3;
    for (int j = t; j < N_; j += 256) {
        xs[j] = xb[j * 3 + 0];
        ys[j] = xb[j * 3 + 1];
        zs[j] = xb[j * 3 + 2];
    }
    __syncthreads();

    float cx = xs[n], cy = ys[n], cz = zs[n];
    uint ku[16];
    #pragma unroll
    for (int k = 0; k < 16; ++k) {
        int j = lane + (k << 6);
        float dx = xs[j] - cx, dy = ys[j] - cy, dz = zs[j] - cz;
        float d = dx * dx + dy * dy + dz * dz;
        ku[k] = (__float_as_uint(d) & 0xFFFFFC00u) | (uint)j;
    }

    int* op = idx + (size_t)(b * N_ + n) * K_;
    for (int s = 0; s < K_; ++s) {
        uint m = ku[0];
        #pragma unroll
        for (int k = 1; k < 16; ++k) m = min(m, ku[k]);
        #pragma unroll
        for (int o = 32; o; o >>= 1) m = min(m, (uint)__shfl_xor((int)m, o));
        int j = (int)(m & 1023u);
        if ((j & 63) == lane) {
            op[s] = j;
            ku[j >> 6] = 0xFFFFFFFFu;
        }
    }
}

// ---------------------------------------------------------------------------
// conv_pos fused -> h1 fp16 plane (B,3,N,128).
// ---------------------------------------------------------------------------
__global__ __launch_bounds__(128) void convpos_kernel(const float* __restrict__ x,
                                                      const int* __restrict__ idx,
                                                      const float* __restrict__ Wf,
                                                      const float* __restrict__ Wd,
                                                      half_t* __restrict__ h1) {
    int bn = blockIdx.x;
    int b = bn >> 10, n = bn & 1023;
    const float* xb = x + (size_t)b * N_ * 3;

    __shared__ float nb[K_][3];
    __shared__ float ctr[3];
    int t = threadIdx.x;
    if (t < K_) {
        int j = idx[(size_t)bn * K_ + t];
        nb[t][0] = xb[j * 3 + 0];
        nb[t][1] = xb[j * 3 + 1];
        nb[t][2] = xb[j * 3 + 2];
    }
    if (t == K_) {
        ctr[0] = xb[n * 3 + 0]; ctr[1] = xb[n * 3 + 1]; ctr[2] = xb[n * 3 + 2];
    }
    __syncthreads();

    float cx = ctr[0], cy = ctr[1], cz = ctr[2];
    float wf0 = Wf[t * 3 + 0], wf1 = Wf[t * 3 + 1], wf2 = Wf[t * 3 + 2];
    float wd0 = Wd[t * 3 + 0], wd1 = Wd[t * 3 + 1], wd2 = Wd[t * 3 + 2];

    float ax = 0.f, ay = 0.f, az = 0.f;
    #pragma unroll 4
    for (int kk = 0; kk < K_; ++kk) {
        float nx = nb[kk][0], ny = nb[kk][1], nz = nb[kk][2];
        float ex = nx - cx, ey = ny - cy, ez = nz - cz;
        float rx = ny * cz - nz * cy;
        float ry = nz * cx - nx * cz;
        float rz = nx * cy - ny * cx;
        float fx = wf0 * ex + wf1 * cx + wf2 * rx;
        float fy = wf0 * ey + wf1 * cy + wf2 * ry;
        float fz = wf0 * ez + wf1 * cz + wf2 * rz;
        float gx = wd0 * ex + wd1 * cx + wd2 * rx;
        float gy = wd0 * ey + wd1 * cy + wd2 * ry;
        float gz = wd0 * ez + wd1 * cz + wd2 * rz;
        float dot = fx * gx + fy * gy + fz * gz;
        float dsq = gx * gx + gy * gy + gz * gz + EPS_;
        float coef = dot / dsq;
        float qx, qy, qz;
        if (dot >= 0.f) { qx = fx; qy = fy; qz = fz; }
        else            { qx = fx - coef * gx; qy = fy - coef * gy; qz = fz - coef * gz; }
        ax += 0.2f * fx + 0.8f * qx;
        ay += 0.2f * fy + 0.8f * qy;
        az += 0.2f * fz + 0.8f * qz;
    }
    const float inv = 1.0f / (float)K_;
    size_t r0 = ((size_t)b * 3) * N_ + n;
    h1[(r0) * H_ + t]          = (half_t)(ax * inv);
    h1[(r0 + N_) * H_ + t]     = (half_t)(ay * inv);
    h1[(r0 + 2 * N_) * H_ + t] = (half_t)(az * inv);
}

// ---------------------------------------------------------------------------
// 3-v fused fp16 MFMA GEMM (R9 structure), tile 64(m) x 32(n), 4 waves,
// single fp16 weight plane (6 MFMAs/k-iter). XOR-swizzled LDS, 10 KB.
// RELU_MODE: 0=none, 1=VN-relu p from pA (stride O), 2=VN-relu p=[pA
// (o<128, stride 128) | P fp32 bcast]. Optional rowAdd.
// ---------------------------------------------------------------------------
template<int RELU_MODE, bool HAS_ROWADD>
__global__ __launch_bounds__(256) void gemm3v(const half_t* __restrict__ W,
                                              int lda,
                                              const half_t* __restrict__ A,
                                              int C,
                                              const half_t* __restrict__ pA,
                                              const float* __restrict__ P,
                                              const float* __restrict__ rowAdd,
                                              half_t* __restrict__ outA,
                                              int O) {
    __shared__ __align__(16) half_t Ah[64 * 32];
    __shared__ __align__(16) half_t Bs[3][32 * 32];

    const int t = threadIdx.x;
    const int lane = t & 63, wave = t >> 6;
    const int wm = wave >> 1, wn = wave & 1;
    const int l16 = lane & 15, quad = lane >> 4;
    const int sw = (quad ^ (l16 & 3)) * 8;
    const int m0 = blockIdx.y * 64;
    const int b  = blockIdx.z;
    const int n0 = blockIdx.x * 32;

    f4_t acc[3][2];
    #pragma unroll
    for (int v = 0; v < 3; ++v)
        #pragma unroll
        for (int i = 0; i < 2; ++i)
            #pragma unroll
            for (int e = 0; e < 4; ++e) acc[v][i][e] = 0.f;

    for (int k0 = 0; k0 < C; k0 += 32) {
        {   // A: 64 rows x 4 chunks = 256 (one per thread)
            int row = t >> 2, ch = t & 3;
            size_t g = (size_t)(m0 + row) * lda + k0 + ch * 8;
            int ld = row * 32 + ((ch ^ (row & 3)) * 8);
            *(uint4*)(Ah + ld) = *(const uint4*)(W + g);
        }
        #pragma unroll
        for (int c = t; c < 384; c += 256) {   // B: 3 x 32 rows x 4 chunks
            int v = c >> 7, rem = c & 127;
            int row = rem >> 2, ch = rem & 3;
            size_t g = (size_t)((b * 3 + v) * N_ + n0 + row) * C + k0 + ch * 8;
            int ld = row * 32 + ((ch ^ (row & 3)) * 8);
            *(uint4*)(Bs[v] + ld) = *(const uint4*)(A + g);
        }
        __syncthreads();
        h8_t ah[2], bh[3];
        #pragma unroll
        for (int i = 0; i < 2; ++i) {
            int ar = wm * 32 + i * 16 + l16;
            ah[i] = *(const h8_t*)(Ah + ar * 32 + sw);
        }
        #pragma unroll
        for (int v = 0; v < 3; ++v) {
            int br = wn * 16 + l16;
            bh[v] = *(const h8_t*)(Bs[v] + br * 32 + sw);
        }
        #pragma unroll
        for (int v = 0; v < 3; ++v)
            #pragma unroll
            for (int i = 0; i < 2; ++i)
                acc[v][i] = __builtin_amdgcn_mfma_f32_16x16x32_f16(
                    ah[i], bh[v], acc[v][i], 0, 0, 0);
        __syncthreads();
    }

    const int n = n0 + wn * 16 + l16;
    const size_t row0 = (size_t)(b * 3) * N_ + n;
    #pragma unroll
    for (int i = 0; i < 2; ++i) {
        int o = m0 + wm * 32 + i * 16 + quad * 4;
        f4_t d[3];
        #pragma unroll
        for (int v = 0; v < 3; ++v) {
            d[v] = acc[v][i];
            if (HAS_ROWADD) {
                float4 ra = *(const float4*)(rowAdd + (size_t)(b * 3 + v) * O + o);
                d[v][0] += ra.x; d[v][1] += ra.y; d[v][2] += ra.z; d[v][3] += ra.w;
            }
        }
        if (RELU_MODE == 0) {
            #pragma unroll
            for (int v = 0; v < 3; ++v)
                st4h(outA, (row0 + (size_t)v * N_) * O + o, d[v]);
        } else {
            f4_t p[3];
            if (RELU_MODE == 1) {
                #pragma unroll
                for (int v = 0; v < 3; ++v)
                    p[v] = ld4h(pA, (row0 + (size_t)v * N_) * O + o);
            } else {
                if (o < 128) {
                    #pragma unroll
                    for (int v = 0; v < 3; ++v)
                        p[v] = ld4h(pA, (row0 + (size_t)v * N_) * 128 + o);
                } else {
                    #pragma unroll
                    for (int e = 0; e < 4; ++e) {
                        const float* Pc = P + (size_t)(b * 128 + o - 128 + e) * 3;
                        p[0][e] = Pc[0]; p[1][e] = Pc[1]; p[2][e] = Pc[2];
                    }
                }
            }
            f4_t q[3];
            #pragma unroll
            for (int e = 0; e < 4; ++e) {
                float dot = p[0][e] * d[0][e] + p[1][e] * d[1][e] + p[2][e] * d[2][e];
                float dsq = d[0][e] * d[0][e] + d[1][e] * d[1][e] + d[2][e] * d[2][e] + EPS_;
                float cf = dot / dsq;
                if (dot >= 0.f) { q[0][e] = p[0][e]; q[1][e] = p[1][e]; q[2][e] = p[2][e]; }
                else {
                    q[0][e] = p[0][e] - cf * d[0][e];
                    q[1][e] = p[1][e] - cf * d[1][e];
                    q[2][e] = p[2][e] - cf * d[2][e];
                }
            }
            #pragma unroll
            for (int v = 0; v < 3; ++v)
                st4h(outA, (row0 + (size_t)v * N_) * O + o, q[v]);
        }
    }
}

// ---------------------------------------------------------------------------
// 3-v dual-segment GEMM (h = Ws*hidden + W1*a1 + rowAdd), tile 64x32, single
// fp16 weight plane, fused pool partials; optional h writes. O=128.
// Pp layout: [((b*32 + ntile)*2 + wn) * 384 + o*3 + v]  (64 slots per b)
// ---------------------------------------------------------------------------
template<bool HAS_ROWADD, bool WRITE_OUT>
__global__ __launch_bounds__(256) void gemm3v_dual(const half_t* __restrict__ W0,
                                                   int lda0, int C0,
                                                   const half_t* __restrict__ A0,
                                                   const half_t* __restrict__ W1,
                                                   int lda1, int C1,
                                                   const half_t* __restrict__ A1,
                                                   const float* __restrict__ rowAdd,
                                                   half_t* __restrict__ outA,
                                                   float* __restrict__ Pp) {
    constexpr int O = 128;
    __shared__ __align__(16) half_t Ah[64 * 32];
    __shared__ __align__(16) half_t Bs[3][32 * 32];

    const int t = threadIdx.x;
    const int lane = t & 63, wave = t >> 6;
    const int wm = wave >> 1, wn = wave & 1;
    const int l16 = lane & 15, quad = lane >> 4;
    const int sw = (quad ^ (l16 & 3)) * 8;
    const int m0 = blockIdx.y * 64;
    const int b  = blockIdx.z;
    const int n0 = blockIdx.x * 32;

    f4_t acc[3][2];
    #pragma unroll
    for (int v = 0; v < 3; ++v)
        #pragma unroll
        for (int i = 0; i < 2; ++i)
            #pragma unroll
            for (int e = 0; e < 4; ++e) acc[v][i][e] = 0.f;

    const int Ct = C0 + C1;
    for (int k0 = 0; k0 < Ct; k0 += 32) {
        const bool seg = (k0 >= C0);
        const half_t* wp = seg ? W1 : W0;
        const half_t* ag = seg ? A1 : A0;
        const int lda = seg ? lda1 : lda0;
        const int cs  = seg ? C1 : C0;
        const int kk  = seg ? (k0 - C0) : k0;
        {
            int row = t >> 2, ch = t & 3;
            size_t g = (size_t)(m0 + row) * lda + kk + ch * 8;
            int ld = row * 32 + ((ch ^ (row & 3)) * 8);
            *(uint4*)(Ah + ld) = *(const uint4*)(wp + g);
        }
        #pragma unroll
        for (int c = t; c < 384; c += 256) {
            int v = c >> 7, rem = c & 127;
            int row = rem >> 2, ch = rem & 3;
            size_t g = (size_t)((b * 3 + v) * N_ + n0 + row) * cs + kk + ch * 8;
            int ld = row * 32 + ((ch ^ (row & 3)) * 8);
            *(uint4*)(Bs[v] + ld) = *(const uint4*)(ag + g);
        }
        __syncthreads();
        h8_t ah[2], bh[3];
        #pragma unroll
        for (int i = 0; i < 2; ++i) {
            int ar = wm * 32 + i * 16 + l16;
            ah[i] = *(const h8_t*)(Ah + ar * 32 + sw);
        }
        #pragma unroll
        for (int v = 0; v < 3; ++v) {
            int br = wn * 16 + l16;
            bh[v] = *(const h8_t*)(Bs[v] + br * 32 + sw);
        }
        #pragma unroll
        for (int v = 0; v < 3; ++v)
            #pragma unroll
            for (int i = 0; i < 2; ++i)
                acc[v][i] = __builtin_amdgcn_mfma_f32_16x16x32_f16(
                    ah[i], bh[v], acc[v][i], 0, 0, 0);
        __syncthreads();
    }

    const int n = n0 + wn * 16 + l16;
    const size_t row0 = (size_t)(b * 3) * N_ + n;
    const size_t slot = ((size_t)b * 32 + blockIdx.x) * 2 + wn;
    #pragma unroll
    for (int i = 0; i < 2; ++i) {
        int o = m0 + wm * 32 + i * 16 + quad * 4;
        f4_t d[3];
        #pragma unroll
        for (int v = 0; v < 3; ++v) {
            d[v] = acc[v][i];
            if (HAS_ROWADD) {
                float4 ra = *(const float4*)(rowAdd + (size_t)(b * 3 + v) * O + o);
                d[v][0] += ra.x; d[v][1] += ra.y; d[v][2] += ra.z; d[v][3] += ra.w;
            }
            if (WRITE_OUT)
                st4h(outA, (row0 + (size_t)v * N_) * O + o, d[v]);
        }
        // reduce over 16-lane n-group
        #pragma unroll
        for (int v = 0; v < 3; ++v)
            #pragma unroll
            for (int e = 0; e < 4; ++e) {
                float s = d[v][e];
                s += __shfl_xor(s, 1);
                s += __shfl_xor(s, 2);
                s += __shfl_xor(s, 4);
                s += __shfl_xor(s, 8);
                d[v][e] = s;
            }
        if (l16 == 0) {
            #pragma unroll
            for (int v = 0; v < 3; ++v)
                #pragma unroll
                for (int e = 0; e < 4; ++e)
                    Pp[slot * 384 + (size_t)(o + e) * 3 + v] = d[v][e];
        }
    }
}

// ---------------------------------------------------------------------------
// Fused pool stage 2 + (optional) rowadd for the NEXT block.
// Block s = b*3+v (24 blocks, 256 thr). Computes P[b,:,v] from Pp (64 slots),
// then addD0[s][:] / addWs[s][:] from the next block's fp32 weights.
// ---------------------------------------------------------------------------
template<bool ROWADD>
__global__ __launch_bounds__(256) void pool_rowadd(const float* __restrict__ Pp,
                                                   const float* __restrict__ Wd0n,
                                                   const float* __restrict__ Wsn,
                                                   float* __restrict__ P,
                                                   float* __restrict__ addD0,
                                                   float* __restrict__ addWs) {
    int s = blockIdx.x;
    int b = s / 3, v = s % 3;
    int t = threadIdx.x;
    __shared__ float Pl[128];
    if (t < 128) {
        float sum = 0.f;
        const float* p = Pp + (size_t)b * 64 * 384 + (size_t)t * 3 + v;
        #pragma unroll 4
        for (int sl = 0; sl < 64; ++sl) sum += p[(size_t)sl * 384];
        sum *= (1.0f / (float)N_);
        Pl[t] = sum;
        P[(size_t)(b * 128 + t) * 3 + v] = sum;
    }
    __syncthreads();
    if (ROWADD) {
        float sum = 0.f;
        const float* wr = Wd0n + (size_t)t * 256 + 128;
        #pragma unroll 8
        for (int c = 0; c < 128; ++c) sum += wr[c] * Pl[c];
        addD0[(size_t)s * 256 + t] = sum;
        if (t < 128) {
            const float* wr2 = Wsn + (size_t)t * 256 + 128;
            float s2 = 0.f;
            #pragma unroll 8
            for (int c = 0; c < 128; ++c) s2 += wr2[c] * Pl[c];
            addWs[(size_t)s * 128 + t] = s2;
        }
    }
}

// ---------------------------------------------------------------------------
// Final stage (fp32, exact)
// ---------------------------------------------------------------------------
__global__ __launch_bounds__(128) void final_kernel(const float* __restrict__ P,
                                                    const float* __restrict__ Wd,
                                                    const float* __restrict__ Wc,
                                                    float* __restrict__ out) {
    int b = blockIdx.x;
    int t = threadIdx.x;
    __shared__ float hid[H_][3];
    __shared__ float act[H_][3];
    const float* Pb = P + (size_t)b * H_ * 3;
    hid[t][0] = Pb[t * 3 + 0];
    hid[t][1] = Pb[t * 3 + 1];
    hid[t][2] = Pb[t * 3 + 2];
    __syncthreads();

    float d0 = 0.f, d1 = 0.f, d2 = 0.f;
    const float* wd = Wd + (size_t)t * H_;
    for (int c = 0; c < H_; ++c) {
        float w = wd[c];
        d0 += w * hid[c][0]; d1 += w * hid[c][1]; d2 += w * hid[c][2];
    }
    float p0 = hid[t][0], p1 = hid[t][1], p2 = hid[t][2];
    float dot = p0 * d0 + p1 * d1 + p2 * d2;
    float dsq = d0 * d0 + d1 * d1 + d2 * d2 + EPS_;
    float cf = dot / dsq;
    float q0, q1, q2;
    if (dot >= 0.f) { q0 = p0; q1 = p1; q2 = p2; }
    else            { q0 = p0 - cf * d0; q1 = p1 - cf * d1; q2 = p2 - cf * d2; }
    act[t][0] = 0.2f * p0 + 0.8f * q0;
    act[t][1] = 0.2f * p1 + 0.8f * q1;
    act[t][2] = 0.2f * p2 + 0.8f * q2;
    __syncthreads();

    float o0 = 0.f, o1 = 0.f, o2 = 0.f;
    const float* wc = Wc + (size_t)t * H_;
    for (int c = 0; c < H_; ++c) {
        float w = wc[c];
        o0 += w * act[c][0]; o1 += w * act[c][1]; o2 += w * act[c][2];
    }
    size_t ob = ((size_t)b * H_ + t) * 3;
    out[ob + 0] = o0; out[ob + 1] = o1; out[ob + 2] = o2;
}

// ---------------------------------------------------------------------------
extern "C" void kernel_launch(void* const* d_in, const int* in_sizes, int n_in,
                              void* d_out, int out_size, void* d_ws, size_t ws_size,
                              hipStream_t stream) {
    const float* x   = (const float*)d_in[0];
    const float* Wf  = (const float*)d_in[1];
    const float* Wdp = (const float*)d_in[2];
    const float* Wfc = (const float*)d_in[3];
    const float* Wd0 = (const float*)d_in[4];
    const float* W0  = (const float*)d_in[5];
    const float* Wd1 = (const float*)d_in[6];
    const float* W1  = (const float*)d_in[7];
    const float* Wsc = (const float*)d_in[8];
    const float* Wda = (const float*)d_in[9];
    const float* Wc  = (const float*)d_in[10];
    float* out = (float*)d_out;
    (void)in_sizes; (void)n_in; (void)out_size; (void)ws_size;

    char* ws = (char*)d_ws;
    size_t off = 0;
    auto alloc = [&](size_t bytes) {
        void* p = ws + off;
        off = (off + bytes + 255) & ~(size_t)255;
        return p;
    };
    const size_t e128 = (size_t)R_ * 128;
    const size_t e256 = (size_t)R_ * 256;
    int*    idx   = (int*)   alloc((size_t)B_ * N_ * K_ * sizeof(int));
    half_t* wAll  = (half_t*)alloc((size_t)W_TOT * 2);
    half_t* h1F   = (half_t*)alloc(e128 * 2);
    half_t* HdF   = (half_t*)alloc(e256 * 2);
    half_t* a0F   = (half_t*)alloc(e256 * 2);
    half_t* netF  = (half_t*)alloc(e128 * 2);
    half_t* a1F   = (half_t*)alloc(e128 * 2);
    half_t* hF[2] = { (half_t*)alloc(e128 * 2), (half_t*)alloc(e128 * 2) };
    float*  addD0 = (float*) alloc(24 * 256 * 4);
    float*  addWs = (float*) alloc(24 * 128 * 4);
    float*  Pp    = (float*) alloc((size_t)B_ * 64 * 384 * 4);
    float*  P     = (float*) alloc((size_t)B_ * 128 * 3 * 4);

    const half_t* whFc = wAll + OFF_FC;
    const half_t* whD0 = wAll + OFF_D0;
    const half_t* whW0 = wAll + OFF_W0;
    const half_t* whD1 = wAll + OFF_D1;
    const half_t* whW1 = wAll + OFF_W1;
    const half_t* whWs = wAll + OFF_WS;

    hipLaunchKernelGGL(cvt_all, dim3((W_TOT + 255) / 256), dim3(256), 0, stream,
                       Wfc, Wd0, W0, Wd1, W1, Wsc, wAll);
    hipLaunchKernelGGL(knn_wave, dim3(B_ * N_ / 4), dim3(256), 0, stream, x, idx);
    hipLaunchKernelGGL(convpos_kernel, dim3(B_ * N_), dim3(128), 0, stream,
                       x, idx, Wf, Wdp, h1F);

    // fc_pos: Hd = Wfc (256x128) * h1
    gemm3v<0, false><<<dim3(32, 4, 8), 256, 0, stream>>>(
        whFc, 128, h1F, 128, nullptr, nullptr, nullptr, HdF, 256);

    for (int i = 0; i < 4; ++i) {
        int cur = i & 1, prv = cur ^ 1;
        if (i == 0) {
            // a0 = vnrelu(Hd, Wd0*Hd)
            gemm3v<1, false><<<dim3(32, 4, 8), 256, 0, stream>>>(
                whD0, 256, HdF, 256, HdF, nullptr, nullptr, a0F, 256);
        } else {
            // a0 = vnrelu([h|P], Wd0_left*h + rowAdd)   (addD0 from prev pool)
            gemm3v<2, true><<<dim3(32, 4, 8), 256, 0, stream>>>(
                whD0 + (size_t)i * 65536, 256, hF[prv], 128,
                hF[prv], P, addD0, a0F, 256);
        }
        // net = W0 * a0
        gemm3v<0, false><<<dim3(32, 2, 8), 256, 0, stream>>>(
            whW0 + (size_t)i * 32768, 256, a0F, 256,
            nullptr, nullptr, nullptr, netF, 128);
        // a1 = vnrelu(net, Wd1*net)
        gemm3v<1, false><<<dim3(32, 2, 8), 256, 0, stream>>>(
            whD1 + (size_t)i * 16384, 128, netF, 128,
            netF, nullptr, nullptr, a1F, 128);
        // h = [Ws | W1] * [hidden ; a1] (+rowAdd) ; fused pool partials
        if (i == 0) {
            gemm3v_dual<false, true><<<dim3(32, 2, 8), 256, 0, stream>>>(
                whWs, 256, 256, HdF,
                whW1, 128, 128, a1F,
                nullptr, hF[cur], Pp);
        } else if (i < 3) {
            gemm3v_dual<true, true><<<dim3(32, 2, 8), 256, 0, stream>>>(
                whWs + (size_t)i * 32768, 256, 128, hF[prv],
                whW1 + (size_t)i * 16384, 128, 128, a1F,
                addWs, hF[cur], Pp);
        } else {
            gemm3v_dual<true, false><<<dim3(32, 2, 8), 256, 0, stream>>>(
                whWs + (size_t)i * 32768, 256, 128, hF[prv],
                whW1 + (size_t)i * 16384, 128, 128, a1F,
                addWs, nullptr, Pp);
        }
        // pool (+ rowadd for next block, using next block's fp32 weights)
        if (i < 3) {
            hipLaunchKernelGGL((pool_rowadd<true>), dim3(24), dim3(256), 0, stream,
                               Pp, Wd0 + (size_t)(i + 1) * 65536,
                               Wsc + (size_t)(i + 1) * 32768, P, addD0, addWs);
        } else {
            hipLaunchKernelGGL((pool_rowadd<false>), dim3(24), dim3(256), 0, stream,
                               Pp, nullptr, nullptr, P, nullptr, nullptr);
        }
    }

    hipLaunchKernelGGL(final_kernel, dim3(B_), dim3(128), 0, stream, P, Wda, Wc, out);
}

// Round 12
// 336.754 us; speedup vs baseline: 1.4778x; 1.0856x over previous
//
#include <hip/hip_runtime.h>
#include <cfloat>
#include <cstdint>

#define B_   8
#define N_   1024
#define H_   128
#define K_   20
#define EPS_ 1e-6f
#define R_   (B_ * 3 * N_)

typedef _Float16 half_t;
typedef _Float16 h8_t __attribute__((ext_vector_type(8)));
typedef _Float16 h4_t __attribute__((ext_vector_type(4)));
typedef __attribute__((ext_vector_type(4))) float f4_t;

__device__ inline f4_t ld4h(const half_t* __restrict__ p, size_t off) {
    h4_t x = *(const h4_t*)(p + off);
    f4_t r;
    r[0] = (float)x[0]; r[1] = (float)x[1]; r[2] = (float)x[2]; r[3] = (float)x[3];
    return r;
}
__device__ inline void st4h(half_t* __restrict__ p, size_t off, f4_t v) {
    h4_t o;
    o[0] = (half_t)v[0]; o[1] = (half_t)v[1]; o[2] = (half_t)v[2]; o[3] = (half_t)v[3];
    *(h4_t*)(p + off) = o;
}

// ---------------------------------------------------------------------------
// All-weights fp32 -> fp16.
// ---------------------------------------------------------------------------
#define OFF_FC 0
#define OFF_D0 32768
#define OFF_W0 294912
#define OFF_D1 425984
#define OFF_W1 491520
#define OFF_WS 557056
#define W_TOT  688128
__global__ __launch_bounds__(256) void cvt_all(const float* __restrict__ Wfc,
                                               const float* __restrict__ Wd0,
                                               const float* __restrict__ W0,
                                               const float* __restrict__ Wd1,
                                               const float* __restrict__ W1,
                                               const float* __restrict__ Wsc,
                                               half_t* __restrict__ w) {
    int i = blockIdx.x * 256 + threadIdx.x;
    if (i >= W_TOT) return;
    const float* src; int off;
    if (i < OFF_W0)      { if (i < OFF_D0) { src = Wfc; off = OFF_FC; }
                           else            { src = Wd0; off = OFF_D0; } }
    else if (i < OFF_W1) { if (i < OFF_D1) { src = W0;  off = OFF_W0; }
                           else            { src = Wd1; off = OFF_D1; } }
    else                 { if (i < OFF_WS) { src = W1;  off = OFF_W1; }
                           else            { src = Wsc; off = OFF_WS; } }
    w[i] = (half_t)src[i - off];
}

// ---------------------------------------------------------------------------
// kNN: LDS cloud + 20 rounds of packed-u32 butterfly min (R11-verified).
// ---------------------------------------------------------------------------
__global__ __launch_bounds__(256) void knn_wave(const float* __restrict__ x,
                                                int* __restrict__ idx) {
    __shared__ float xs[N_], ys[N_], zs[N_];
    int t = threadIdx.x;
    int wv = t >> 6, lane = t & 63;
    int b = blockIdx.x >> 8;
    int n = (blockIdx.x & 255) * 4 + wv;
    const float* xb = x + (size_t)b * N_ * 3;
    for (int j = t; j < N_; j += 256) {
        xs[j] = xb[j * 3 + 0];
        ys[j] = xb[j * 3 + 1];
        zs[j] = xb[j * 3 + 2];
    }
    __syncthreads();

    float cx = xs[n], cy = ys[n], cz = zs[n];
    uint ku[16];
    #pragma unroll
    for (int k = 0; k < 16; ++k) {
        int j = lane + (k << 6);
        float dx = xs[j] - cx, dy = ys[j] - cy, dz = zs[j] - cz;
        float d = dx * dx + dy * dy + dz * dz;
        ku[k] = (__float_as_uint(d) & 0xFFFFFC00u) | (uint)j;
    }

    int* op = idx + (size_t)(b * N_ + n) * K_;
    for (int s = 0; s < K_; ++s) {
        uint m = ku[0];
        #pragma unroll
        for (int k = 1; k < 16; ++k) m = min(m, ku[k]);
        #pragma unroll
        for (int o = 32; o; o >>= 1) m = min(m, (uint)__shfl_xor((int)m, o));
        int j = (int)(m & 1023u);
        if ((j & 63) == lane) {
            op[s] = j;
            ku[j >> 6] = 0xFFFFFFFFu;
        }
    }
}

// ---------------------------------------------------------------------------
// conv_pos fused -> h1 fp16 plane (B,3,N,128).
// ---------------------------------------------------------------------------
__global__ __launch_bounds__(128) void convpos_kernel(const float* __restrict__ x,
                                                      const int* __restrict__ idx,
                                                      const float* __restrict__ Wf,
                                                      const float* __restrict__ Wd,
                                                      half_t* __restrict__ h1) {
    int bn = blockIdx.x;
    int b = bn >> 10, n = bn & 1023;
    const float* xb = x + (size_t)b * N_ * 3;

    __shared__ float nb[K_][3];
    __shared__ float ctr[3];
    int t = threadIdx.x;
    if (t < K_) {
        int j = idx[(size_t)bn * K_ + t];
        nb[t][0] = xb[j * 3 + 0];
        nb[t][1] = xb[j * 3 + 1];
        nb[t][2] = xb[j * 3 + 2];
    }
    if (t == K_) {
        ctr[0] = xb[n * 3 + 0]; ctr[1] = xb[n * 3 + 1]; ctr[2] = xb[n * 3 + 2];
    }
    __syncthreads();

    float cx = ctr[0], cy = ctr[1], cz = ctr[2];
    float wf0 = Wf[t * 3 + 0], wf1 = Wf[t * 3 + 1], wf2 = Wf[t * 3 + 2];
    float wd0 = Wd[t * 3 + 0], wd1 = Wd[t * 3 + 1], wd2 = Wd[t * 3 + 2];

    float ax = 0.f, ay = 0.f, az = 0.f;
    #pragma unroll 4
    for (int kk = 0; kk < K_; ++kk) {
        float nx = nb[kk][0], ny = nb[kk][1], nz = nb[kk][2];
        float ex = nx - cx, ey = ny - cy, ez = nz - cz;
        float rx = ny * cz - nz * cy;
        float ry = nz * cx - nx * cz;
        float rz = nx * cy - ny * cx;
        float fx = wf0 * ex + wf1 * cx + wf2 * rx;
        float fy = wf0 * ey + wf1 * cy + wf2 * ry;
        float fz = wf0 * ez + wf1 * cz + wf2 * rz;
        float gx = wd0 * ex + wd1 * cx + wd2 * rx;
        float gy = wd0 * ey + wd1 * cy + wd2 * ry;
        float gz = wd0 * ez + wd1 * cz + wd2 * rz;
        float dot = fx * gx + fy * gy + fz * gz;
        float dsq = gx * gx + gy * gy + gz * gz + EPS_;
        float coef = dot / dsq;
        float qx, qy, qz;
        if (dot >= 0.f) { qx = fx; qy = fy; qz = fz; }
        else            { qx = fx - coef * gx; qy = fy - coef * gy; qz = fz - coef * gz; }
        ax += 0.2f * fx + 0.8f * qx;
        ay += 0.2f * fy + 0.8f * qy;
        az += 0.2f * fz + 0.8f * qz;
    }
    const float inv = 1.0f / (float)K_;
    size_t r0 = ((size_t)b * 3) * N_ + n;
    h1[(r0) * H_ + t]          = (half_t)(ax * inv);
    h1[(r0 + N_) * H_ + t]     = (half_t)(ay * inv);
    h1[(r0 + 2 * N_) * H_ + t] = (half_t)(az * inv);
}

// ---------------------------------------------------------------------------
// 3-v fused fp16 MFMA GEMM (R11 structure): tile 64(m) x 32(n), 4 waves,
// single fp16 weight plane. Used for fc_pos and the a0 (Wd0) GEMM.
// ---------------------------------------------------------------------------
template<int RELU_MODE, bool HAS_ROWADD>
__global__ __launch_bounds__(256) void gemm3v(const half_t* __restrict__ W,
                                              int lda,
                                              const half_t* __restrict__ A,
                                              int C,
                                              const half_t* __restrict__ pA,
                                              const float* __restrict__ P,
                                              const float* __restrict__ rowAdd,
                                              half_t* __restrict__ outA,
                                              int O) {
    __shared__ __align__(16) half_t Ah[64 * 32];
    __shared__ __align__(16) half_t Bs[3][32 * 32];

    const int t = threadIdx.x;
    const int lane = t & 63, wave = t >> 6;
    const int wm = wave >> 1, wn = wave & 1;
    const int l16 = lane & 15, quad = lane >> 4;
    const int sw = (quad ^ (l16 & 3)) * 8;
    const int m0 = blockIdx.y * 64;
    const int b  = blockIdx.z;
    const int n0 = blockIdx.x * 32;

    f4_t acc[3][2];
    #pragma unroll
    for (int v = 0; v < 3; ++v)
        #pragma unroll
        for (int i = 0; i < 2; ++i)
            #pragma unroll
            for (int e = 0; e < 4; ++e) acc[v][i][e] = 0.f;

    for (int k0 = 0; k0 < C; k0 += 32) {
        {
            int row = t >> 2, ch = t & 3;
            size_t g = (size_t)(m0 + row) * lda + k0 + ch * 8;
            int ld = row * 32 + ((ch ^ (row & 3)) * 8);
            *(uint4*)(Ah + ld) = *(const uint4*)(W + g);
        }
        #pragma unroll
        for (int c = t; c < 384; c += 256) {
            int v = c >> 7, rem = c & 127;
            int row = rem >> 2, ch = rem & 3;
            size_t g = (size_t)((b * 3 + v) * N_ + n0 + row) * C + k0 + ch * 8;
            int ld = row * 32 + ((ch ^ (row & 3)) * 8);
            *(uint4*)(Bs[v] + ld) = *(const uint4*)(A + g);
        }
        __syncthreads();
        h8_t ah[2], bh[3];
        #pragma unroll
        for (int i = 0; i < 2; ++i) {
            int ar = wm * 32 + i * 16 + l16;
            ah[i] = *(const h8_t*)(Ah + ar * 32 + sw);
        }
        #pragma unroll
        for (int v = 0; v < 3; ++v) {
            int br = wn * 16 + l16;
            bh[v] = *(const h8_t*)(Bs[v] + br * 32 + sw);
        }
        #pragma unroll
        for (int v = 0; v < 3; ++v)
            #pragma unroll
            for (int i = 0; i < 2; ++i)
                acc[v][i] = __builtin_amdgcn_mfma_f32_16x16x32_f16(
                    ah[i], bh[v], acc[v][i], 0, 0, 0);
        __syncthreads();
    }

    const int n = n0 + wn * 16 + l16;
    const size_t row0 = (size_t)(b * 3) * N_ + n;
    #pragma unroll
    for (int i = 0; i < 2; ++i) {
        int o = m0 + wm * 32 + i * 16 + quad * 4;
        f4_t d[3];
        #pragma unroll
        for (int v = 0; v < 3; ++v) {
            d[v] = acc[v][i];
            if (HAS_ROWADD) {
                float4 ra = *(const float4*)(rowAdd + (size_t)(b * 3 + v) * O + o);
                d[v][0] += ra.x; d[v][1] += ra.y; d[v][2] += ra.z; d[v][3] += ra.w;
            }
        }
        if (RELU_MODE == 0) {
            #pragma unroll
            for (int v = 0; v < 3; ++v)
                st4h(outA, (row0 + (size_t)v * N_) * O + o, d[v]);
        } else {
            f4_t p[3];
            if (RELU_MODE == 1) {
                #pragma unroll
                for (int v = 0; v < 3; ++v)
                    p[v] = ld4h(pA, (row0 + (size_t)v * N_) * O + o);
            } else {
                if (o < 128) {
                    #pragma unroll
                    for (int v = 0; v < 3; ++v)
                        p[v] = ld4h(pA, (row0 + (size_t)v * N_) * 128 + o);
                } else {
                    #pragma unroll
                    for (int e = 0; e < 4; ++e) {
                        const float* Pc = P + (size_t)(b * 128 + o - 128 + e) * 3;
                        p[0][e] = Pc[0]; p[1][e] = Pc[1]; p[2][e] = Pc[2];
                    }
                }
            }
            f4_t q[3];
            #pragma unroll
            for (int e = 0; e < 4; ++e) {
                float dot = p[0][e] * d[0][e] + p[1][e] * d[1][e] + p[2][e] * d[2][e];
                float dsq = d[0][e] * d[0][e] + d[1][e] * d[1][e] + d[2][e] * d[2][e] + EPS_;
                float cf = dot / dsq;
                if (dot >= 0.f) { q[0][e] = p[0][e]; q[1][e] = p[1][e]; q[2][e] = p[2][e]; }
                else {
                    q[0][e] = p[0][e] - cf * d[0][e];
                    q[1][e] = p[1][e] - cf * d[1][e];
                    q[2][e] = p[2][e] - cf * d[2][e];
                }
            }
            #pragma unroll
            for (int v = 0; v < 3; ++v)
                st4h(outA, (row0 + (size_t)v * N_) * O + o, q[v]);
        }
    }
}

// ---------------------------------------------------------------------------
// block_tail: fused net -> a1 -> h(+pool) for one resnet block.
// Block = (n-tile 16, b); 4 waves; wave wm covers o = wm*32..+31, all 3 v.
// S1: net = W0(128x256) * a0           -> net in LDS (never global)
// S2: d1 = Wd1(128x128) * net ; a1 = vnrelu(net, d1) -> a1 in LDS
// S3: h = Ws * h_prev + W1 * a1 (+rowAdd) ; pool partials ; write h
// LDS persistent buffers use chunk XOR-swizzle ((ch>>3)^(n&7)).
// ---------------------------------------------------------------------------
__device__ inline void st_sw(half_t* __restrict__ buf, int v, int n, int o, f4_t val) {
    int phys = ((o >> 3) ^ (n & 7)) * 8 + (o & 7);
    half_t* p = buf + (v * 16 + n) * 128 + phys;
    h4_t h;
    h[0] = (half_t)val[0]; h[1] = (half_t)val[1];
    h[2] = (half_t)val[2]; h[3] = (half_t)val[3];
    *(h4_t*)p = h;
}
__device__ inline f4_t ld_sw4(const half_t* __restrict__ buf, int v, int n, int o) {
    int phys = ((o >> 3) ^ (n & 7)) * 8 + (o & 7);
    const half_t* p = buf + (v * 16 + n) * 128 + phys;
    h4_t x = *(const h4_t*)p;
    f4_t r;
    r[0] = (float)x[0]; r[1] = (float)x[1]; r[2] = (float)x[2]; r[3] = (float)x[3];
    return r;
}

template<bool FIRST, bool WRITE_OUT>
__global__ __launch_bounds__(256) void block_tail(const half_t* __restrict__ W0,
                                                  const half_t* __restrict__ Wd1,
                                                  const half_t* __restrict__ Ws,
                                                  const half_t* __restrict__ W1,
                                                  const half_t* __restrict__ a0,
                                                  const half_t* __restrict__ hprev,
                                                  const float* __restrict__ rowAdd,
                                                  half_t* __restrict__ outH,
                                                  float* __restrict__ Pp) {
    constexpr int C0 = FIRST ? 256 : 128;     // h_prev channel count
    __shared__ __align__(16) half_t As[128 * 32];      // A staging (8 KB)
    __shared__ __align__(16) half_t Bst[3 * 16 * 32];  // B staging (3 KB)
    __shared__ __align__(16) half_t netL[3 * 16 * 128];// 12 KB
    __shared__ __align__(16) half_t a1L[3 * 16 * 128]; // 12 KB

    const int t = threadIdx.x;
    const int lane = t & 63, wm = t >> 6;     // 4 waves, wave = o-range
    const int l16 = lane & 15, quad = lane >> 4;
    const int sw = (quad ^ (l16 & 3)) * 8;
    const int b  = blockIdx.z;
    const int nt = blockIdx.x;
    const int n0 = nt * 16;
    const int n  = n0 + l16;
    const size_t row0 = (size_t)(b * 3) * N_ + n;

    f4_t acc[3][2];
    auto zero_acc = [&]() {
        #pragma unroll
        for (int v = 0; v < 3; ++v)
            #pragma unroll
            for (int i = 0; i < 2; ++i)
                #pragma unroll
                for (int e = 0; e < 4; ++e) acc[v][i][e] = 0.f;
    };

    // ------------- S1: net = W0 * a0 (C=256) -------------
    zero_acc();
    for (int k0 = 0; k0 < 256; k0 += 32) {
        #pragma unroll
        for (int c = t; c < 512; c += 256) {            // A: 128 rows x 4 chunks
            int row = c >> 2, ch = c & 3;
            size_t g = (size_t)row * 256 + k0 + ch * 8;
            *(uint4*)(As + row * 32 + ((ch ^ (row & 3)) * 8)) = *(const uint4*)(W0 + g);
        }
        if (t < 192) {                                   // B: 3v x 16n x 4 chunks
            int v = t >> 6, rem = t & 63;
            int row = rem >> 2, ch = rem & 3;
            size_t g = (size_t)((b * 3 + v) * N_ + n0 + row) * 256 + k0 + ch * 8;
            *(uint4*)(Bst + (v * 16 + row) * 32 + ((ch ^ (row & 3)) * 8)) =
                *(const uint4*)(a0 + g);
        }
        __syncthreads();
        h8_t ah[2], bh[3];
        #pragma unroll
        for (int i = 0; i < 2; ++i)
            ah[i] = *(const h8_t*)(As + (wm * 32 + i * 16 + l16) * 32 + sw);
        #pragma unroll
        for (int v = 0; v < 3; ++v)
            bh[v] = *(const h8_t*)(Bst + (v * 16 + l16) * 32 + sw);
        #pragma unroll
        for (int v = 0; v < 3; ++v)
            #pragma unroll
            for (int i = 0; i < 2; ++i)
                acc[v][i] = __builtin_amdgcn_mfma_f32_16x16x32_f16(
                    ah[i], bh[v], acc[v][i], 0, 0, 0);
        __syncthreads();
    }
    #pragma unroll
    for (int i = 0; i < 2; ++i) {
        int o = wm * 32 + i * 16 + quad * 4;
        #pragma unroll
        for (int v = 0; v < 3; ++v) st_sw(netL, v, l16, o, acc[v][i]);
    }

    // ------------- S2: d1 = Wd1 * net ; a1 = vnrelu(net, d1) -------------
    zero_acc();
    for (int k0 = 0; k0 < 128; k0 += 32) {
        #pragma unroll
        for (int c = t; c < 512; c += 256) {
            int row = c >> 2, ch = c & 3;
            size_t g = (size_t)row * 128 + k0 + ch * 8;
            *(uint4*)(As + row * 32 + ((ch ^ (row & 3)) * 8)) = *(const uint4*)(Wd1 + g);
        }
        __syncthreads();                                  // orders netL writes too
        h8_t ah[2], bh[3];
        #pragma unroll
        for (int i = 0; i < 2; ++i)
            ah[i] = *(const h8_t*)(As + (wm * 32 + i * 16 + l16) * 32 + sw);
        int lc = (k0 >> 3) + quad;
        #pragma unroll
        for (int v = 0; v < 3; ++v)
            bh[v] = *(const h8_t*)(netL + (v * 16 + l16) * 128 + (lc ^ (l16 & 7)) * 8);
        #pragma unroll
        for (int v = 0; v < 3; ++v)
            #pragma unroll
            for (int i = 0; i < 2; ++i)
                acc[v][i] = __builtin_amdgcn_mfma_f32_16x16x32_f16(
                    ah[i], bh[v], acc[v][i], 0, 0, 0);
        __syncthreads();
    }
    #pragma unroll
    for (int i = 0; i < 2; ++i) {
        int o = wm * 32 + i * 16 + quad * 4;
        f4_t p[3], q[3];
        #pragma unroll
        for (int v = 0; v < 3; ++v) p[v] = ld_sw4(netL, v, l16, o);
        #pragma unroll
        for (int e = 0; e < 4; ++e) {
            float dot = p[0][e] * acc[0][i][e] + p[1][e] * acc[1][i][e] + p[2][e] * acc[2][i][e];
            float dsq = acc[0][i][e] * acc[0][i][e] + acc[1][i][e] * acc[1][i][e]
                      + acc[2][i][e] * acc[2][i][e] + EPS_;
            float cf = dot / dsq;
            if (dot >= 0.f) { q[0][e] = p[0][e]; q[1][e] = p[1][e]; q[2][e] = p[2][e]; }
            else {
                q[0][e] = p[0][e] - cf * acc[0][i][e];
                q[1][e] = p[1][e] - cf * acc[1][i][e];
                q[2][e] = p[2][e] - cf * acc[2][i][e];
            }
        }
        #pragma unroll
        for (int v = 0; v < 3; ++v) st_sw(a1L, v, l16, o, q[v]);
    }

    // ------------- S3: h = Ws * h_prev + W1 * a1 (+rowAdd) -------------
    zero_acc();
    for (int k0 = 0; k0 < C0; k0 += 32) {                 // segment 0
        #pragma unroll
        for (int c = t; c < 512; c += 256) {
            int row = c >> 2, ch = c & 3;
            size_t g = (size_t)row * 256 + k0 + ch * 8;   // Ws lda = 256 always
            *(uint4*)(As + row * 32 + ((ch ^ (row & 3)) * 8)) = *(const uint4*)(Ws + g);
        }
        if (t < 192) {
            int v = t >> 6, rem = t & 63;
            int row = rem >> 2, ch = rem & 3;
            size_t g = (size_t)((b * 3 + v) * N_ + n0 + row) * C0 + k0 + ch * 8;
            *(uint4*)(Bst + (v * 16 + row) * 32 + ((ch ^ (row & 3)) * 8)) =
                *(const uint4*)(hprev + g);
        }
        __syncthreads();                                   // orders a1L writes too
        h8_t ah[2], bh[3];
        #pragma unroll
        for (int i = 0; i < 2; ++i)
            ah[i] = *(const h8_t*)(As + (wm * 32 + i * 16 + l16) * 32 + sw);
        #pragma unroll
        for (int v = 0; v < 3; ++v)
            bh[v] = *(const h8_t*)(Bst + (v * 16 + l16) * 32 + sw);
        #pragma unroll
        for (int v = 0; v < 3; ++v)
            #pragma unroll
            for (int i = 0; i < 2; ++i)
                acc[v][i] = __builtin_amdgcn_mfma_f32_16x16x32_f16(
                    ah[i], bh[v], acc[v][i], 0, 0, 0);
        __syncthreads();
    }
    for (int k0 = 0; k0 < 128; k0 += 32) {                 // segment 1 (a1 in LDS)
        #pragma unroll
        for (int c = t; c < 512; c += 256) {
            int row = c >> 2, ch = c & 3;
            size_t g = (size_t)row * 128 + k0 + ch * 8;
            *(uint4*)(As + row * 32 + ((ch ^ (row & 3)) * 8)) = *(const uint4*)(W1 + g);
        }
        __syncthreads();
        h8_t ah[2], bh[3];
        #pragma unroll
        for (int i = 0; i < 2; ++i)
            ah[i] = *(const h8_t*)(As + (wm * 32 + i * 16 + l16) * 32 + sw);
        int lc = (k0 >> 3) + quad;
        #pragma unroll
        for (int v = 0; v < 3; ++v)
            bh[v] = *(const h8_t*)(a1L + (v * 16 + l16) * 128 + (lc ^ (l16 & 7)) * 8);
        #pragma unroll
        for (int v = 0; v < 3; ++v)
            #pragma unroll
            for (int i = 0; i < 2; ++i)
                acc[v][i] = __builtin_amdgcn_mfma_f32_16x16x32_f16(
                    ah[i], bh[v], acc[v][i], 0, 0, 0);
        __syncthreads();
    }

    const size_t slot = (size_t)b * 64 + nt;
    #pragma unroll
    for (int i = 0; i < 2; ++i) {
        int o = wm * 32 + i * 16 + quad * 4;
        f4_t d[3];
        #pragma unroll
        for (int v = 0; v < 3; ++v) {
            d[v] = acc[v][i];
            if (!FIRST) {
                float4 ra = *(const float4*)(rowAdd + (size_t)(b * 3 + v) * 128 + o);
                d[v][0] += ra.x; d[v][1] += ra.y; d[v][2] += ra.z; d[v][3] += ra.w;
            }
            if (WRITE_OUT)
                st4h(outH, (row0 + (size_t)v * N_) * 128 + o, d[v]);
        }
        #pragma unroll
        for (int v = 0; v < 3; ++v)
            #pragma unroll
            for (int e = 0; e < 4; ++e) {
                float s = d[v][e];
                s += __shfl_xor(s, 1);
                s += __shfl_xor(s, 2);
                s += __shfl_xor(s, 4);
                s += __shfl_xor(s, 8);
                d[v][e] = s;
            }
        if (l16 == 0) {
            #pragma unroll
            for (int v = 0; v < 3; ++v)
                #pragma unroll
                for (int e = 0; e < 4; ++e)
                    Pp[slot * 384 + (size_t)(o + e) * 3 + v] = d[v][e];
        }
    }
}

// ---------------------------------------------------------------------------
// Fused pool stage 2 + (optional) rowadd for the NEXT block.
// ---------------------------------------------------------------------------
template<bool ROWADD>
__global__ __launch_bounds__(256) void pool_rowadd(const float* __restrict__ Pp,
                                                   const float* __restrict__ Wd0n,
                                                   const float* __restrict__ Wsn,
                                                   float* __restrict__ P,
                                                   float* __restrict__ addD0,
                                                   float* __restrict__ addWs) {
    int s = blockIdx.x;
    int b = s / 3, v = s % 3;
    int t = threadIdx.x;
    __shared__ float Pl[128];
    if (t < 128) {
        float sum = 0.f;
        const float* p = Pp + (size_t)b * 64 * 384 + (size_t)t * 3 + v;
        #pragma unroll 4
        for (int sl = 0; sl < 64; ++sl) sum += p[(size_t)sl * 384];
        sum *= (1.0f / (float)N_);
        Pl[t] = sum;
        P[(size_t)(b * 128 + t) * 3 + v] = sum;
    }
    __syncthreads();
    if (ROWADD) {
        float sum = 0.f;
        const float* wr = Wd0n + (size_t)t * 256 + 128;
        #pragma unroll 8
        for (int c = 0; c < 128; ++c) sum += wr[c] * Pl[c];
        addD0[(size_t)s * 256 + t] = sum;
        if (t < 128) {
            const float* wr2 = Wsn + (size_t)t * 256 + 128;
            float s2 = 0.f;
            #pragma unroll 8
            for (int c = 0; c < 128; ++c) s2 += wr2[c] * Pl[c];
            addWs[(size_t)s * 128 + t] = s2;
        }
    }
}

// ---------------------------------------------------------------------------
// Final stage (fp32, exact)
// ---------------------------------------------------------------------------
__global__ __launch_bounds__(128) void final_kernel(const float* __restrict__ P,
                                                    const float* __restrict__ Wd,
                                                    const float* __restrict__ Wc,
                                                    float* __restrict__ out) {
    int b = blockIdx.x;
    int t = threadIdx.x;
    __shared__ float hid[H_][3];
    __shared__ float act[H_][3];
    const float* Pb = P + (size_t)b * H_ * 3;
    hid[t][0] = Pb[t * 3 + 0];
    hid[t][1] = Pb[t * 3 + 1];
    hid[t][2] = Pb[t * 3 + 2];
    __syncthreads();

    float d0 = 0.f, d1 = 0.f, d2 = 0.f;
    const float* wd = Wd + (size_t)t * H_;
    for (int c = 0; c < H_; ++c) {
        float w = wd[c];
        d0 += w * hid[c][0]; d1 += w * hid[c][1]; d2 += w * hid[c][2];
    }
    float p0 = hid[t][0], p1 = hid[t][1], p2 = hid[t][2];
    float dot = p0 * d0 + p1 * d1 + p2 * d2;
    float dsq = d0 * d0 + d1 * d1 + d2 * d2 + EPS_;
    float cf = dot / dsq;
    float q0, q1, q2;
    if (dot >= 0.f) { q0 = p0; q1 = p1; q2 = p2; }
    else            { q0 = p0 - cf * d0; q1 = p1 - cf * d1; q2 = p2 - cf * d2; }
    act[t][0] = 0.2f * p0 + 0.8f * q0;
    act[t][1] = 0.2f * p1 + 0.8f * q1;
    act[t][2] = 0.2f * p2 + 0.8f * q2;
    __syncthreads();

    float o0 = 0.f, o1 = 0.f, o2 = 0.f;
    const float* wc = Wc + (size_t)t * H_;
    for (int c = 0; c < H_; ++c) {
        float w = wc[c];
        o0 += w * act[c][0]; o1 += w * act[c][1]; o2 += w * act[c][2];
    }
    size_t ob = ((size_t)b * H_ + t) * 3;
    out[ob + 0] = o0; out[ob + 1] = o1; out[ob + 2] = o2;
}

// ---------------------------------------------------------------------------
extern "C" void kernel_launch(void* const* d_in, const int* in_sizes, int n_in,
                              void* d_out, int out_size, void* d_ws, size_t ws_size,
                              hipStream_t stream) {
    const float* x   = (const float*)d_in[0];
    const float* Wf  = (const float*)d_in[1];
    const float* Wdp = (const float*)d_in[2];
    const float* Wfc = (const float*)d_in[3];
    const float* Wd0 = (const float*)d_in[4];
    const float* W0  = (const float*)d_in[5];
    const float* Wd1 = (const float*)d_in[6];
    const float* W1  = (const float*)d_in[7];
    const float* Wsc = (const float*)d_in[8];
    const float* Wda = (const float*)d_in[9];
    const float* Wc  = (const float*)d_in[10];
    float* out = (float*)d_out;
    (void)in_sizes; (void)n_in; (void)out_size; (void)ws_size;

    char* ws = (char*)d_ws;
    size_t off = 0;
    auto alloc = [&](size_t bytes) {
        void* p = ws + off;
        off = (off + bytes + 255) & ~(size_t)255;
        return p;
    };
    const size_t e128 = (size_t)R_ * 128;
    const size_t e256 = (size_t)R_ * 256;
    int*    idx   = (int*)   alloc((size_t)B_ * N_ * K_ * sizeof(int));
    half_t* wAll  = (half_t*)alloc((size_t)W_TOT * 2);
    half_t* h1F   = (half_t*)alloc(e128 * 2);
    half_t* HdF   = (half_t*)alloc(e256 * 2);
    half_t* a0F   = (half_t*)alloc(e256 * 2);
    half_t* hF[2] = { (half_t*)alloc(e128 * 2), (half_t*)alloc(e128 * 2) };
    float*  addD0 = (float*) alloc(24 * 256 * 4);
    float*  addWs = (float*) alloc(24 * 128 * 4);
    float*  Pp    = (float*) alloc((size_t)B_ * 64 * 384 * 4);
    float*  P     = (float*) alloc((size_t)B_ * 128 * 3 * 4);

    const half_t* whFc = wAll + OFF_FC;
    const half_t* whD0 = wAll + OFF_D0;
    const half_t* whW0 = wAll + OFF_W0;
    const half_t* whD1 = wAll + OFF_D1;
    const half_t* whW1 = wAll + OFF_W1;
    const half_t* whWs = wAll + OFF_WS;

    hipLaunchKernelGGL(cvt_all, dim3((W_TOT + 255) / 256), dim3(256), 0, stream,
                       Wfc, Wd0, W0, Wd1, W1, Wsc, wAll);
    hipLaunchKernelGGL(knn_wave, dim3(B_ * N_ / 4), dim3(256), 0, stream, x, idx);
    hipLaunchKernelGGL(convpos_kernel, dim3(B_ * N_), dim3(128), 0, stream,
                       x, idx, Wf, Wdp, h1F);

    // fc_pos: Hd = Wfc (256x128) * h1
    gemm3v<0, false><<<dim3(32, 4, 8), 256, 0, stream>>>(
        whFc, 128, h1F, 128, nullptr, nullptr, nullptr, HdF, 256);

    for (int i = 0; i < 4; ++i) {
        int cur = i & 1, prv = cur ^ 1;
        // a0 = vnrelu(hidden, Wd0*hidden_left + rowAdd)
        if (i == 0) {
            gemm3v<1, false><<<dim3(32, 4, 8), 256, 0, stream>>>(
                whD0, 256, HdF, 256, HdF, nullptr, nullptr, a0F, 256);
        } else {
            gemm3v<2, true><<<dim3(32, 4, 8), 256, 0, stream>>>(
                whD0 + (size_t)i * 65536, 256, hF[prv], 128,
                hF[prv], P, addD0, a0F, 256);
        }
        // fused tail: net -> a1 -> h(+pool)
        if (i == 0) {
            block_tail<true, true><<<dim3(64, 1, 8), 256, 0, stream>>>(
                whW0, whD1, whWs, whW1, a0F, HdF, nullptr, hF[cur], Pp);
        } else if (i < 3) {
            block_tail<false, true><<<dim3(64, 1, 8), 256, 0, stream>>>(
                whW0 + (size_t)i * 32768, whD1 + (size_t)i * 16384,
                whWs + (size_t)i * 32768, whW1 + (size_t)i * 16384,
                a0F, hF[prv], addWs, hF[cur], Pp);
        } else {
            block_tail<false, false><<<dim3(64, 1, 8), 256, 0, stream>>>(
                whW0 + (size_t)i * 32768, whD1 + (size_t)i * 16384,
                whWs + (size_t)i * 32768, whW1 + (size_t)i * 16384,
                a0F, hF[prv], addWs, nullptr, Pp);
        }
        // pool (+ rowadd for next block)
        if (i < 3) {
            hipLaunchKernelGGL((pool_rowadd<true>), dim3(24), dim3(256), 0, stream,
                               Pp, Wd0 + (size_t)(i + 1) * 65536,
                               Wsc + (size_t)(i + 1) * 32768, P, addD0, addWs);
        } else {
            hipLaunchKernelGGL((pool_rowadd<false>), dim3(24), dim3(256), 0, stream,
                               Pp, nullptr, nullptr, P, nullptr, nullptr);
        }
    }

    hipLaunchKernelGGL(final_kernel, dim3(B_), dim3(128), 0, stream, P, Wda, Wc, out);
}

// Round 13
// 302.095 us; speedup vs baseline: 1.6473x; 1.1147x over previous
//
#include <hip/hip_runtime.h>
#include <cfloat>
#include <cstdint>

#define B_   8
#define N_   1024
#define H_   128
#define K_   20
#define EPS_ 1e-6f
#define R_   (B_ * 3 * N_)

typedef _Float16 half_t;
typedef _Float16 h8_t __attribute__((ext_vector_type(8)));
typedef _Float16 h4_t __attribute__((ext_vector_type(4)));
typedef __attribute__((ext_vector_type(4))) float f4_t;

__device__ inline f4_t ld4h(const half_t* __restrict__ p, size_t off) {
    h4_t x = *(const h4_t*)(p + off);
    f4_t r;
    r[0] = (float)x[0]; r[1] = (float)x[1]; r[2] = (float)x[2]; r[3] = (float)x[3];
    return r;
}
__device__ inline void st4h(half_t* __restrict__ p, size_t off, f4_t v) {
    h4_t o;
    o[0] = (half_t)v[0]; o[1] = (half_t)v[1]; o[2] = (half_t)v[2]; o[3] = (half_t)v[3];
    *(h4_t*)(p + off) = o;
}

// ---------------------------------------------------------------------------
// All-weights fp32 -> fp16.
// ---------------------------------------------------------------------------
#define OFF_FC 0
#define OFF_D0 32768
#define OFF_W0 294912
#define OFF_D1 425984
#define OFF_W1 491520
#define OFF_WS 557056
#define W_TOT  688128
__global__ __launch_bounds__(256) void cvt_all(const float* __restrict__ Wfc,
                                               const float* __restrict__ Wd0,
                                               const float* __restrict__ W0,
                                               const float* __restrict__ Wd1,
                                               const float* __restrict__ W1,
                                               const float* __restrict__ Wsc,
                                               half_t* __restrict__ w) {
    int i = blockIdx.x * 256 + threadIdx.x;
    if (i >= W_TOT) return;
    const float* src; int off;
    if (i < OFF_W0)      { if (i < OFF_D0) { src = Wfc; off = OFF_FC; }
                           else            { src = Wd0; off = OFF_D0; } }
    else if (i < OFF_W1) { if (i < OFF_D1) { src = W0;  off = OFF_W0; }
                           else            { src = Wd1; off = OFF_D1; } }
    else                 { if (i < OFF_WS) { src = W1;  off = OFF_W1; }
                           else            { src = Wsc; off = OFF_WS; } }
    w[i] = (half_t)src[i - off];
}

// ---------------------------------------------------------------------------
// kNN: LDS cloud + 20 rounds of packed-u32 butterfly min (R11-verified).
// ---------------------------------------------------------------------------
__global__ __launch_bounds__(256) void knn_wave(const float* __restrict__ x,
                                                int* __restrict__ idx) {
    __shared__ float xs[N_], ys[N_], zs[N_];
    int t = threadIdx.x;
    int wv = t >> 6, lane = t & 63;
    int b = blockIdx.x >> 8;
    int n = (blockIdx.x & 255) * 4 + wv;
    const float* xb = x + (size_t)b * N_ * 3;
    for (int j = t; j < N_; j += 256) {
        xs[j] = xb[j * 3 + 0];
        ys[j] = xb[j * 3 + 1];
        zs[j] = xb[j * 3 + 2];
    }
    __syncthreads();

    float cx = xs[n], cy = ys[n], cz = zs[n];
    uint ku[16];
    #pragma unroll
    for (int k = 0; k < 16; ++k) {
        int j = lane + (k << 6);
        float dx = xs[j] - cx, dy = ys[j] - cy, dz = zs[j] - cz;
        float d = dx * dx + dy * dy + dz * dz;
        ku[k] = (__float_as_uint(d) & 0xFFFFFC00u) | (uint)j;
    }

    int* op = idx + (size_t)(b * N_ + n) * K_;
    for (int s = 0; s < K_; ++s) {
        uint m = ku[0];
        #pragma unroll
        for (int k = 1; k < 16; ++k) m = min(m, ku[k]);
        #pragma unroll
        for (int o = 32; o; o >>= 1) m = min(m, (uint)__shfl_xor((int)m, o));
        int j = (int)(m & 1023u);
        if ((j & 63) == lane) {
            op[s] = j;
            ku[j >> 6] = 0xFFFFFFFFu;
        }
    }
}

// ---------------------------------------------------------------------------
// conv_pos fused -> h1 fp16 plane (B,3,N,128).
// ---------------------------------------------------------------------------
__global__ __launch_bounds__(128) void convpos_kernel(const float* __restrict__ x,
                                                      const int* __restrict__ idx,
                                                      const float* __restrict__ Wf,
                                                      const float* __restrict__ Wd,
                                                      half_t* __restrict__ h1) {
    int bn = blockIdx.x;
    int b = bn >> 10, n = bn & 1023;
    const float* xb = x + (size_t)b * N_ * 3;

    __shared__ float nb[K_][3];
    __shared__ float ctr[3];
    int t = threadIdx.x;
    if (t < K_) {
        int j = idx[(size_t)bn * K_ + t];
        nb[t][0] = xb[j * 3 + 0];
        nb[t][1] = xb[j * 3 + 1];
        nb[t][2] = xb[j * 3 + 2];
    }
    if (t == K_) {
        ctr[0] = xb[n * 3 + 0]; ctr[1] = xb[n * 3 + 1]; ctr[2] = xb[n * 3 + 2];
    }
    __syncthreads();

    float cx = ctr[0], cy = ctr[1], cz = ctr[2];
    float wf0 = Wf[t * 3 + 0], wf1 = Wf[t * 3 + 1], wf2 = Wf[t * 3 + 2];
    float wd0 = Wd[t * 3 + 0], wd1 = Wd[t * 3 + 1], wd2 = Wd[t * 3 + 2];

    float ax = 0.f, ay = 0.f, az = 0.f;
    #pragma unroll 4
    for (int kk = 0; kk < K_; ++kk) {
        float nx = nb[kk][0], ny = nb[kk][1], nz = nb[kk][2];
        float ex = nx - cx, ey = ny - cy, ez = nz - cz;
        float rx = ny * cz - nz * cy;
        float ry = nz * cx - nx * cz;
        float rz = nx * cy - ny * cx;
        float fx = wf0 * ex + wf1 * cx + wf2 * rx;
        float fy = wf0 * ey + wf1 * cy + wf2 * ry;
        float fz = wf0 * ez + wf1 * cz + wf2 * rz;
        float gx = wd0 * ex + wd1 * cx + wd2 * rx;
        float gy = wd0 * ey + wd1 * cy + wd2 * ry;
        float gz = wd0 * ez + wd1 * cz + wd2 * rz;
        float dot = fx * gx + fy * gy + fz * gz;
        float dsq = gx * gx + gy * gy + gz * gz + EPS_;
        float coef = dot / dsq;
        float qx, qy, qz;
        if (dot >= 0.f) { qx = fx; qy = fy; qz = fz; }
        else            { qx = fx - coef * gx; qy = fy - coef * gy; qz = fz - coef * gz; }
        ax += 0.2f * fx + 0.8f * qx;
        ay += 0.2f * fy + 0.8f * qy;
        az += 0.2f * fz + 0.8f * qz;
    }
    const float inv = 1.0f / (float)K_;
    size_t r0 = ((size_t)b * 3) * N_ + n;
    h1[(r0) * H_ + t]          = (half_t)(ax * inv);
    h1[(r0 + N_) * H_ + t]     = (half_t)(ay * inv);
    h1[(r0 + 2 * N_) * H_ + t] = (half_t)(az * inv);
}

// ---------------------------------------------------------------------------
// fc_pos GEMM: Hd = Wfc(256x128) * h1, tile 64(m) x 32(n), 4 waves.
// ---------------------------------------------------------------------------
__global__ __launch_bounds__(256) void fc_gemm(const half_t* __restrict__ W,
                                               const half_t* __restrict__ A,
                                               half_t* __restrict__ outA) {
    __shared__ __align__(16) half_t Ah[64 * 32];
    __shared__ __align__(16) half_t Bs[3][32 * 32];

    const int t = threadIdx.x;
    const int lane = t & 63, wave = t >> 6;
    const int wm = wave >> 1, wn = wave & 1;
    const int l16 = lane & 15, quad = lane >> 4;
    const int sw = (quad ^ (l16 & 3)) * 8;
    const int m0 = blockIdx.y * 64;
    const int b  = blockIdx.z;
    const int n0 = blockIdx.x * 32;

    f4_t acc[3][2];
    #pragma unroll
    for (int v = 0; v < 3; ++v)
        #pragma unroll
        for (int i = 0; i < 2; ++i)
            #pragma unroll
            for (int e = 0; e < 4; ++e) acc[v][i][e] = 0.f;

    for (int k0 = 0; k0 < 128; k0 += 32) {
        {
            int row = t >> 2, ch = t & 3;
            size_t g = (size_t)(m0 + row) * 128 + k0 + ch * 8;
            *(uint4*)(Ah + row * 32 + ((ch ^ (row & 3)) * 8)) = *(const uint4*)(W + g);
        }
        #pragma unroll
        for (int c = t; c < 384; c += 256) {
            int v = c >> 7, rem = c & 127;
            int row = rem >> 2, ch = rem & 3;
            size_t g = (size_t)((b * 3 + v) * N_ + n0 + row) * 128 + k0 + ch * 8;
            *(uint4*)(Bs[v] + row * 32 + ((ch ^ (row & 3)) * 8)) = *(const uint4*)(A + g);
        }
        __syncthreads();
        h8_t ah[2], bh[3];
        #pragma unroll
        for (int i = 0; i < 2; ++i)
            ah[i] = *(const h8_t*)(Ah + (wm * 32 + i * 16 + l16) * 32 + sw);
        #pragma unroll
        for (int v = 0; v < 3; ++v)
            bh[v] = *(const h8_t*)(Bs[v] + (wn * 16 + l16) * 32 + sw);
        #pragma unroll
        for (int v = 0; v < 3; ++v)
            #pragma unroll
            for (int i = 0; i < 2; ++i)
                acc[v][i] = __builtin_amdgcn_mfma_f32_16x16x32_f16(
                    ah[i], bh[v], acc[v][i], 0, 0, 0);
        __syncthreads();
    }

    const int n = n0 + wn * 16 + l16;
    const size_t row0 = (size_t)(b * 3) * N_ + n;
    #pragma unroll
    for (int i = 0; i < 2; ++i) {
        int o = m0 + wm * 32 + i * 16 + quad * 4;
        #pragma unroll
        for (int v = 0; v < 3; ++v)
            st4h(outA, (row0 + (size_t)v * N_) * 256 + o, acc[v][i]);
    }
}

// ---------------------------------------------------------------------------
// block_full: entire resnet block per (n-tile 16, b) block.
// S0: a0 = vnrelu(hidden, Wd0*hidden(+rowAdd))   -> a0L (LDS)
// S1: net = W0 * a0                              -> netL (LDS)
// S2: a1 = vnrelu(net, Wd1*net)                  -> a1L (LDS)
// S3: h = Ws*h_prev + W1*a1 (+rowAddWs) ; pool partials ; optional h write
// LDS phases (53 KB): hL[0,12K) | a0L[12K,36K) -> As2[12K,20K)+a1L[24K,36K)
//                     | As1[36K,52K) -> netL[36K,48K)   (manual aliasing)
// ---------------------------------------------------------------------------
__device__ inline void stsw128(half_t* __restrict__ buf, int v, int n, int o, f4_t val) {
    int phys = (((o >> 3) ^ (n & 7)) * 8) + (o & 7);
    half_t* p = buf + (v * 16 + n) * 128 + phys;
    h4_t h;
    h[0] = (half_t)val[0]; h[1] = (half_t)val[1];
    h[2] = (half_t)val[2]; h[3] = (half_t)val[3];
    *(h4_t*)p = h;
}
__device__ inline f4_t ldsw128(const half_t* __restrict__ buf, int v, int n, int o) {
    int phys = (((o >> 3) ^ (n & 7)) * 8) + (o & 7);
    const half_t* p = buf + (v * 16 + n) * 128 + phys;
    h4_t x = *(const h4_t*)p;
    f4_t r;
    r[0] = (float)x[0]; r[1] = (float)x[1]; r[2] = (float)x[2]; r[3] = (float)x[3];
    return r;
}
__device__ inline void stsw256(half_t* __restrict__ buf, int v, int n, int o, f4_t val) {
    int phys = (((o >> 3) ^ (n & 7)) * 8) + (o & 7);
    half_t* p = buf + (v * 16 + n) * 256 + phys;
    h4_t h;
    h[0] = (half_t)val[0]; h[1] = (half_t)val[1];
    h[2] = (half_t)val[2]; h[3] = (half_t)val[3];
    *(h4_t*)p = h;
}

template<bool FIRST, bool WRITE_OUT>
__global__ __launch_bounds__(256) void block_full(const half_t* __restrict__ Wd0,
                                                  const half_t* __restrict__ W0,
                                                  const half_t* __restrict__ Wd1,
                                                  const half_t* __restrict__ Ws,
                                                  const half_t* __restrict__ W1,
                                                  const half_t* __restrict__ hprev,
                                                  const float* __restrict__ P,
                                                  const float* __restrict__ addD0,
                                                  const float* __restrict__ addWs,
                                                  half_t* __restrict__ outH,
                                                  float* __restrict__ Pp) {
    __shared__ __align__(16) char smem[53248];
    half_t* hL   = (half_t*)(smem);             // 12 KB (non-FIRST) / Bst (FIRST)
    half_t* Bst  = (half_t*)(smem);             // 3 KB staging (FIRST only)
    half_t* a0L  = (half_t*)(smem + 12288);     // 24 KB
    half_t* As2  = (half_t*)(smem + 12288);     // 8 KB (S2/S3, after a0L dead)
    half_t* a1L  = (half_t*)(smem + 24576);     // 12 KB (after a0L dead)
    half_t* As1  = (half_t*)(smem + 36864);     // 16 KB (S0/S1)
    half_t* netL = (half_t*)(smem + 36864);     // 12 KB (after As1 dead)

    const int t = threadIdx.x;
    const int lane = t & 63, wm = t >> 6;
    const int l16 = lane & 15, quad = lane >> 4;
    const int sw = (quad ^ (l16 & 3)) * 8;
    const int b  = blockIdx.z;
    const int nt = blockIdx.x;
    const int n0 = nt * 16;
    const size_t row0 = (size_t)(b * 3) * N_ + (n0 + l16);

    // ---- load h_prev tile into hL once (non-FIRST) ----
    if (!FIRST) {
        #pragma unroll
        for (int c = t; c < 768; c += 256) {
            int v = c >> 8, rem = c & 255;
            int n = rem >> 4, ch = rem & 15;
            size_t g = (size_t)((b * 3 + v) * N_ + n0 + n) * 128 + ch * 8;
            *(uint4*)(hL + (v * 16 + n) * 128 + ((ch ^ (n & 7)) * 8)) =
                *(const uint4*)(hprev + g);
        }
    }

    // ------------- S0: a0 = vnrelu(hidden, Wd0*hidden(+addD0)) -------------
    {
        constexpr int C = FIRST ? 256 : 128;
        f4_t acc[3][4];
        #pragma unroll
        for (int v = 0; v < 3; ++v)
            #pragma unroll
            for (int i = 0; i < 4; ++i)
                #pragma unroll
                for (int e = 0; e < 4; ++e) acc[v][i][e] = 0.f;

        for (int k0 = 0; k0 < C; k0 += 32) {
            #pragma unroll
            for (int c = t; c < 1024; c += 256) {        // Wd0: 256 rows x 4 chunks
                int row = c >> 2, ch = c & 3;
                size_t g = (size_t)row * 256 + k0 + ch * 8;
                *(uint4*)(As1 + row * 32 + ((ch ^ (row & 3)) * 8)) =
                    *(const uint4*)(Wd0 + g);
            }
            if (FIRST && t < 192) {                      // B staged from Hd global
                int v = t >> 6, rem = t & 63;
                int row = rem >> 2, ch = rem & 3;
                size_t g = (size_t)((b * 3 + v) * N_ + n0 + row) * 256 + k0 + ch * 8;
                *(uint4*)(Bst + (v * 16 + row) * 32 + ((ch ^ (row & 3)) * 8)) =
                    *(const uint4*)(hprev + g);
            }
            __syncthreads();
            h8_t ah[4], bh[3];
            #pragma unroll
            for (int i = 0; i < 4; ++i)
                ah[i] = *(const h8_t*)(As1 + (wm * 64 + i * 16 + l16) * 32 + sw);
            if (FIRST) {
                #pragma unroll
                for (int v = 0; v < 3; ++v)
                    bh[v] = *(const h8_t*)(Bst + (v * 16 + l16) * 32 + sw);
            } else {
                int lc = (k0 >> 3) + quad;
                #pragma unroll
                for (int v = 0; v < 3; ++v)
                    bh[v] = *(const h8_t*)(hL + (v * 16 + l16) * 128 + ((lc ^ (l16 & 7)) * 8));
            }
            #pragma unroll
            for (int v = 0; v < 3; ++v)
                #pragma unroll
                for (int i = 0; i < 4; ++i)
                    acc[v][i] = __builtin_amdgcn_mfma_f32_16x16x32_f16(
                        ah[i], bh[v], acc[v][i], 0, 0, 0);
            __syncthreads();
        }
        // epilogue: relu against p, store a0L
        #pragma unroll
        for (int i = 0; i < 4; ++i) {
            int o = wm * 64 + i * 16 + quad * 4;
            f4_t d[3], p[3];
            #pragma unroll
            for (int v = 0; v < 3; ++v) {
                d[v] = acc[v][i];
                if (!FIRST) {
                    float4 ra = *(const float4*)(addD0 + (size_t)(b * 3 + v) * 256 + o);
                    d[v][0] += ra.x; d[v][1] += ra.y; d[v][2] += ra.z; d[v][3] += ra.w;
                }
            }
            if (FIRST) {
                #pragma unroll
                for (int v = 0; v < 3; ++v)
                    p[v] = ld4h(hprev, (row0 + (size_t)v * N_) * 256 + o);
            } else {
                if (o < 128) {
                    #pragma unroll
                    for (int v = 0; v < 3; ++v)
                        p[v] = ldsw128(hL, v, l16, o);
                } else {
                    #pragma unroll
                    for (int e = 0; e < 4; ++e) {
                        const float* Pc = P + (size_t)(b * 128 + o - 128 + e) * 3;
                        p[0][e] = Pc[0]; p[1][e] = Pc[1]; p[2][e] = Pc[2];
                    }
                }
            }
            f4_t q[3];
            #pragma unroll
            for (int e = 0; e < 4; ++e) {
                float dot = p[0][e] * d[0][e] + p[1][e] * d[1][e] + p[2][e] * d[2][e];
                float dsq = d[0][e] * d[0][e] + d[1][e] * d[1][e] + d[2][e] * d[2][e] + EPS_;
                float cf = dot / dsq;
                if (dot >= 0.f) { q[0][e] = p[0][e]; q[1][e] = p[1][e]; q[2][e] = p[2][e]; }
                else {
                    q[0][e] = p[0][e] - cf * d[0][e];
                    q[1][e] = p[1][e] - cf * d[1][e];
                    q[2][e] = p[2][e] - cf * d[2][e];
                }
            }
            #pragma unroll
            for (int v = 0; v < 3; ++v) stsw256(a0L, v, l16, o, q[v]);
        }
    }

    // ------------- S1: net = W0 * a0 (C=256, a0 in LDS) -------------
    f4_t acc[3][2];
    #pragma unroll
    for (int v = 0; v < 3; ++v)
        #pragma unroll
        for (int i = 0; i < 2; ++i)
            #pragma unroll
            for (int e = 0; e < 4; ++e) acc[v][i][e] = 0.f;

    for (int k0 = 0; k0 < 256; k0 += 32) {
        #pragma unroll
        for (int c = t; c < 512; c += 256) {             // W0: 128 rows x 4 chunks
            int row = c >> 2, ch = c & 3;
            size_t g = (size_t)row * 256 + k0 + ch * 8;
            *(uint4*)(As1 + row * 32 + ((ch ^ (row & 3)) * 8)) = *(const uint4*)(W0 + g);
        }
        __syncthreads();                                 // orders a0L writes too
        h8_t ah[2], bh[3];
        #pragma unroll
        for (int i = 0; i < 2; ++i)
            ah[i] = *(const h8_t*)(As1 + (wm * 32 + i * 16 + l16) * 32 + sw);
        int lc = (k0 >> 3) + quad;
        #pragma unroll
        for (int v = 0; v < 3; ++v)
            bh[v] = *(const h8_t*)(a0L + (v * 16 + l16) * 256 + ((lc ^ (l16 & 7)) * 8));
        #pragma unroll
        for (int v = 0; v < 3; ++v)
            #pragma unroll
            for (int i = 0; i < 2; ++i)
                acc[v][i] = __builtin_amdgcn_mfma_f32_16x16x32_f16(
                    ah[i], bh[v], acc[v][i], 0, 0, 0);
        __syncthreads();
    }
    #pragma unroll
    for (int i = 0; i < 2; ++i) {
        int o = wm * 32 + i * 16 + quad * 4;
        #pragma unroll
        for (int v = 0; v < 3; ++v) stsw128(netL, v, l16, o, acc[v][i]);
    }

    // ------------- S2: a1 = vnrelu(net, Wd1*net) -------------
    #pragma unroll
    for (int v = 0; v < 3; ++v)
        #pragma unroll
        for (int i = 0; i < 2; ++i)
            #pragma unroll
            for (int e = 0; e < 4; ++e) acc[v][i][e] = 0.f;

    for (int k0 = 0; k0 < 128; k0 += 32) {
        #pragma unroll
        for (int c = t; c < 512; c += 256) {
            int row = c >> 2, ch = c & 3;
            size_t g = (size_t)row * 128 + k0 + ch * 8;
            *(uint4*)(As2 + row * 32 + ((ch ^ (row & 3)) * 8)) = *(const uint4*)(Wd1 + g);
        }
        __syncthreads();                                 // orders netL writes too
        h8_t ah[2], bh[3];
        #pragma unroll
        for (int i = 0; i < 2; ++i)
            ah[i] = *(const h8_t*)(As2 + (wm * 32 + i * 16 + l16) * 32 + sw);
        int lc = (k0 >> 3) + quad;
        #pragma unroll
        for (int v = 0; v < 3; ++v)
            bh[v] = *(const h8_t*)(netL + (v * 16 + l16) * 128 + ((lc ^ (l16 & 7)) * 8));
        #pragma unroll
        for (int v = 0; v < 3; ++v)
            #pragma unroll
            for (int i = 0; i < 2; ++i)
                acc[v][i] = __builtin_amdgcn_mfma_f32_16x16x32_f16(
                    ah[i], bh[v], acc[v][i], 0, 0, 0);
        __syncthreads();
    }
    #pragma unroll
    for (int i = 0; i < 2; ++i) {
        int o = wm * 32 + i * 16 + quad * 4;
        f4_t p[3], q[3];
        #pragma unroll
        for (int v = 0; v < 3; ++v) p[v] = ldsw128(netL, v, l16, o);
        #pragma unroll
        for (int e = 0; e < 4; ++e) {
            float dot = p[0][e] * acc[0][i][e] + p[1][e] * acc[1][i][e] + p[2][e] * acc[2][i][e];
            float dsq = acc[0][i][e] * acc[0][i][e] + acc[1][i][e] * acc[1][i][e]
                      + acc[2][i][e] * acc[2][i][e] + EPS_;
            float cf = dot / dsq;
            if (dot >= 0.f) { q[0][e] = p[0][e]; q[1][e] = p[1][e]; q[2][e] = p[2][e]; }
            else {
                q[0][e] = p[0][e] - cf * acc[0][i][e];
                q[1][e] = p[1][e] - cf * acc[1][i][e];
                q[2][e] = p[2][e] - cf * acc[2][i][e];
            }
        }
        #pragma unroll
        for (int v = 0; v < 3; ++v) stsw128(a1L, v, l16, o, q[v]);
    }
    __syncthreads();   // a1L visible before S3 seg1; As2/netL reuse safe below

    // ------------- S3: h = Ws*h_prev + W1*a1 (+addWs) -------------
    #pragma unroll
    for (int v = 0; v < 3; ++v)
        #pragma unroll
        for (int i = 0; i < 2; ++i)
            #pragma unroll
            for (int e = 0; e < 4; ++e) acc[v][i][e] = 0.f;

    {
        constexpr int C0 = FIRST ? 256 : 128;
        for (int k0 = 0; k0 < C0; k0 += 32) {            // segment 0: Ws * h_prev
            #pragma unroll
            for (int c = t; c < 512; c += 256) {
                int row = c >> 2, ch = c & 3;
                size_t g = (size_t)row * 256 + k0 + ch * 8;   // Ws lda = 256
                *(uint4*)(As2 + row * 32 + ((ch ^ (row & 3)) * 8)) = *(const uint4*)(Ws + g);
            }
            if (FIRST && t < 192) {
                int v = t >> 6, rem = t & 63;
                int row = rem >> 2, ch = rem & 3;
                size_t g = (size_t)((b * 3 + v) * N_ + n0 + row) * 256 + k0 + ch * 8;
                *(uint4*)(Bst + (v * 16 + row) * 32 + ((ch ^ (row & 3)) * 8)) =
                    *(const uint4*)(hprev + g);
            }
            __syncthreads();
            h8_t ah[2], bh[3];
            #pragma unroll
            for (int i = 0; i < 2; ++i)
                ah[i] = *(const h8_t*)(As2 + (wm * 32 + i * 16 + l16) * 32 + sw);
            if (FIRST) {
                #pragma unroll
                for (int v = 0; v < 3; ++v)
                    bh[v] = *(const h8_t*)(Bst + (v * 16 + l16) * 32 + sw);
            } else {
                int lc = (k0 >> 3) + quad;
                #pragma unroll
                for (int v = 0; v < 3; ++v)
                    bh[v] = *(const h8_t*)(hL + (v * 16 + l16) * 128 + ((lc ^ (l16 & 7)) * 8));
            }
            #pragma unroll
            for (int v = 0; v < 3; ++v)
                #pragma unroll
                for (int i = 0; i < 2; ++i)
                    acc[v][i] = __builtin_amdgcn_mfma_f32_16x16x32_f16(
                        ah[i], bh[v], acc[v][i], 0, 0, 0);
            __syncthreads();
        }
        for (int k0 = 0; k0 < 128; k0 += 32) {           // segment 1: W1 * a1 (LDS)
            #pragma unroll
            for (int c = t; c < 512; c += 256) {
                int row = c >> 2, ch = c & 3;
                size_t g = (size_t)row * 128 + k0 + ch * 8;
                *(uint4*)(As2 + row * 32 + ((ch ^ (row & 3)) * 8)) = *(const uint4*)(W1 + g);
            }
            __syncthreads();
            h8_t ah[2], bh[3];
            #pragma unroll
            for (int i = 0; i < 2; ++i)
                ah[i] = *(const h8_t*)(As2 + (wm * 32 + i * 16 + l16) * 32 + sw);
            int lc = (k0 >> 3) + quad;
            #pragma unroll
            for (int v = 0; v < 3; ++v)
                bh[v] = *(const h8_t*)(a1L + (v * 16 + l16) * 128 + ((lc ^ (l16 & 7)) * 8));
            #pragma unroll
            for (int v = 0; v < 3; ++v)
                #pragma unroll
                for (int i = 0; i < 2; ++i)
                    acc[v][i] = __builtin_amdgcn_mfma_f32_16x16x32_f16(
                        ah[i], bh[v], acc[v][i], 0, 0, 0);
            __syncthreads();
        }
    }

    const size_t slot = (size_t)b * 64 + nt;
    #pragma unroll
    for (int i = 0; i < 2; ++i) {
        int o = wm * 32 + i * 16 + quad * 4;
        f4_t d[3];
        #pragma unroll
        for (int v = 0; v < 3; ++v) {
            d[v] = acc[v][i];
            if (!FIRST) {
                float4 ra = *(const float4*)(addWs + (size_t)(b * 3 + v) * 128 + o);
                d[v][0] += ra.x; d[v][1] += ra.y; d[v][2] += ra.z; d[v][3] += ra.w;
            }
            if (WRITE_OUT)
                st4h(outH, (row0 + (size_t)v * N_) * 128 + o, d[v]);
        }
        #pragma unroll
        for (int v = 0; v < 3; ++v)
            #pragma unroll
            for (int e = 0; e < 4; ++e) {
                float s = d[v][e];
                s += __shfl_xor(s, 1);
                s += __shfl_xor(s, 2);
                s += __shfl_xor(s, 4);
                s += __shfl_xor(s, 8);
                d[v][e] = s;
            }
        if (l16 == 0) {
            #pragma unroll
            for (int v = 0; v < 3; ++v)
                #pragma unroll
                for (int e = 0; e < 4; ++e)
                    Pp[slot * 384 + (size_t)(o + e) * 3 + v] = d[v][e];
        }
    }
}

// ---------------------------------------------------------------------------
// Fused pool stage 2 + (optional) rowadd for the NEXT block.
// ---------------------------------------------------------------------------
template<bool ROWADD>
__global__ __launch_bounds__(256) void pool_rowadd(const float* __restrict__ Pp,
                                                   const float* __restrict__ Wd0n,
                                                   const float* __restrict__ Wsn,
                                                   float* __restrict__ P,
                                                   float* __restrict__ addD0,
                                                   float* __restrict__ addWs) {
    int s = blockIdx.x;
    int b = s / 3, v = s % 3;
    int t = threadIdx.x;
    __shared__ float Pl[128];
    if (t < 128) {
        float sum = 0.f;
        const float* p = Pp + (size_t)b * 64 * 384 + (size_t)t * 3 + v;
        #pragma unroll 4
        for (int sl = 0; sl < 64; ++sl) sum += p[(size_t)sl * 384];
        sum *= (1.0f / (float)N_);
        Pl[t] = sum;
        P[(size_t)(b * 128 + t) * 3 + v] = sum;
    }
    __syncthreads();
    if (ROWADD) {
        float sum = 0.f;
        const float* wr = Wd0n + (size_t)t * 256 + 128;
        #pragma unroll 8
        for (int c = 0; c < 128; ++c) sum += wr[c] * Pl[c];
        addD0[(size_t)s * 256 + t] = sum;
        if (t < 128) {
            const float* wr2 = Wsn + (size_t)t * 256 + 128;
            float s2 = 0.f;
            #pragma unroll 8
            for (int c = 0; c < 128; ++c) s2 += wr2[c] * Pl[c];
            addWs[(size_t)s * 128 + t] = s2;
        }
    }
}

// ---------------------------------------------------------------------------
// Final stage (fp32, exact)
// ---------------------------------------------------------------------------
__global__ __launch_bounds__(128) void final_kernel(const float* __restrict__ P,
                                                    const float* __restrict__ Wd,
                                                    const float* __restrict__ Wc,
                                                    float* __restrict__ out) {
    int b = blockIdx.x;
    int t = threadIdx.x;
    __shared__ float hid[H_][3];
    __shared__ float act[H_][3];
    const float* Pb = P + (size_t)b * H_ * 3;
    hid[t][0] = Pb[t * 3 + 0];
    hid[t][1] = Pb[t * 3 + 1];
    hid[t][2] = Pb[t * 3 + 2];
    __syncthreads();

    float d0 = 0.f, d1 = 0.f, d2 = 0.f;
    const float* wd = Wd + (size_t)t * H_;
    for (int c = 0; c < H_; ++c) {
        float w = wd[c];
        d0 += w * hid[c][0]; d1 += w * hid[c][1]; d2 += w * hid[c][2];
    }
    float p0 = hid[t][0], p1 = hid[t][1], p2 = hid[t][2];
    float dot = p0 * d0 + p1 * d1 + p2 * d2;
    float dsq = d0 * d0 + d1 * d1 + d2 * d2 + EPS_;
    float cf = dot / dsq;
    float q0, q1, q2;
    if (dot >= 0.f) { q0 = p0; q1 = p1; q2 = p2; }
    else            { q0 = p0 - cf * d0; q1 = p1 - cf * d1; q2 = p2 - cf * d2; }
    act[t][0] = 0.2f * p0 + 0.8f * q0;
    act[t][1] = 0.2f * p1 + 0.8f * q1;
    act[t][2] = 0.2f * p2 + 0.8f * q2;
    __syncthreads();

    float o0 = 0.f, o1 = 0.f, o2 = 0.f;
    const float* wc = Wc + (size_t)t * H_;
    for (int c = 0; c < H_; ++c) {
        float w = wc[c];
        o0 += w * act[c][0]; o1 += w * act[c][1]; o2 += w * act[c][2];
    }
    size_t ob = ((size_t)b * H_ + t) * 3;
    out[ob + 0] = o0; out[ob + 1] = o1; out[ob + 2] = o2;
}

// ---------------------------------------------------------------------------
extern "C" void kernel_launch(void* const* d_in, const int* in_sizes, int n_in,
                              void* d_out, int out_size, void* d_ws, size_t ws_size,
                              hipStream_t stream) {
    const float* x   = (const float*)d_in[0];
    const float* Wf  = (const float*)d_in[1];
    const float* Wdp = (const float*)d_in[2];
    const float* Wfc = (const float*)d_in[3];
    const float* Wd0 = (const float*)d_in[4];
    const float* W0  = (const float*)d_in[5];
    const float* Wd1 = (const float*)d_in[6];
    const float* W1  = (const float*)d_in[7];
    const float* Wsc = (const float*)d_in[8];
    const float* Wda = (const float*)d_in[9];
    const float* Wc  = (const float*)d_in[10];
    float* out = (float*)d_out;
    (void)in_sizes; (void)n_in; (void)out_size; (void)ws_size;

    char* ws = (char*)d_ws;
    size_t off = 0;
    auto alloc = [&](size_t bytes) {
        void* p = ws + off;
        off = (off + bytes + 255) & ~(size_t)255;
        return p;
    };
    const size_t e128 = (size_t)R_ * 128;
    const size_t e256 = (size_t)R_ * 256;
    int*    idx   = (int*)   alloc((size_t)B_ * N_ * K_ * sizeof(int));
    half_t* wAll  = (half_t*)alloc((size_t)W_TOT * 2);
    half_t* h1F   = (half_t*)alloc(e128 * 2);
    half_t* HdF   = (half_t*)alloc(e256 * 2);
    half_t* hF[2] = { (half_t*)alloc(e128 * 2), (half_t*)alloc(e128 * 2) };
    float*  addD0 = (float*) alloc(24 * 256 * 4);
    float*  addWs = (float*) alloc(24 * 128 * 4);
    float*  Pp    = (float*) alloc((size_t)B_ * 64 * 384 * 4);
    float*  P     = (float*) alloc((size_t)B_ * 128 * 3 * 4);

    const half_t* whFc = wAll + OFF_FC;
    const half_t* whD0 = wAll + OFF_D0;
    const half_t* whW0 = wAll + OFF_W0;
    const half_t* whD1 = wAll + OFF_D1;
    const half_t* whW1 = wAll + OFF_W1;
    const half_t* whWs = wAll + OFF_WS;

    hipLaunchKernelGGL(cvt_all, dim3((W_TOT + 255) / 256), dim3(256), 0, stream,
                       Wfc, Wd0, W0, Wd1, W1, Wsc, wAll);
    hipLaunchKernelGGL(knn_wave, dim3(B_ * N_ / 4), dim3(256), 0, stream, x, idx);
    hipLaunchKernelGGL(convpos_kernel, dim3(B_ * N_), dim3(128), 0, stream,
                       x, idx, Wf, Wdp, h1F);

    // fc_pos: Hd = Wfc (256x128) * h1
    fc_gemm<<<dim3(32, 4, 8), 256, 0, stream>>>(whFc, h1F, HdF);

    for (int i = 0; i < 4; ++i) {
        int cur = i & 1, prv = cur ^ 1;
        if (i == 0) {
            block_full<true, true><<<dim3(64, 1, 8), 256, 0, stream>>>(
                whD0, whW0, whD1, whWs, whW1,
                HdF, nullptr, nullptr, nullptr, hF[cur], Pp);
        } else if (i < 3) {
            block_full<false, true><<<dim3(64, 1, 8), 256, 0, stream>>>(
                whD0 + (size_t)i * 65536, whW0 + (size_t)i * 32768,
                whD1 + (size_t)i * 16384, whWs + (size_t)i * 32768,
                whW1 + (size_t)i * 16384,
                hF[prv], P, addD0, addWs, hF[cur], Pp);
        } else {
            block_full<false, false><<<dim3(64, 1, 8), 256, 0, stream>>>(
                whD0 + (size_t)i * 65536, whW0 + (size_t)i * 32768,
                whD1 + (size_t)i * 16384, whWs + (size_t)i * 32768,
                whW1 + (size_t)i * 16384,
                hF[prv], P, addD0, addWs, nullptr, Pp);
        }
        if (i < 3) {
            hipLaunchKernelGGL((pool_rowadd<true>), dim3(24), dim3(256), 0, stream,
                               Pp, Wd0 + (size_t)(i + 1) * 65536,
                               Wsc + (size_t)(i + 1) * 32768, P, addD0, addWs);
        } else {
            hipLaunchKernelGGL((pool_rowadd<false>), dim3(24), dim3(256), 0, stream,
                               Pp, nullptr, nullptr, P, nullptr, nullptr);
        }
    }

    hipLaunchKernelGGL(final_kernel, dim3(B_), dim3(128), 0, stream, P, Wda, Wc, out);
}

// Round 14
// 287.568 us; speedup vs baseline: 1.7305x; 1.0505x over previous
//
#include <hip/hip_runtime.h>
#include <cfloat>
#include <cstdint>

#define B_   8
#define N_   1024
#define H_   128
#define K_   20
#define EPS_ 1e-6f
#define R_   (B_ * 3 * N_)

typedef _Float16 half_t;
typedef _Float16 h8_t __attribute__((ext_vector_type(8)));
typedef _Float16 h4_t __attribute__((ext_vector_type(4)));
typedef __attribute__((ext_vector_type(4))) float f4_t;

__device__ inline void st4h(half_t* __restrict__ p, size_t off, f4_t v) {
    h4_t o;
    o[0] = (half_t)v[0]; o[1] = (half_t)v[1]; o[2] = (half_t)v[2]; o[3] = (half_t)v[3];
    *(h4_t*)(p + off) = o;
}

// ---------------------------------------------------------------------------
// All-weights fp32 -> fp16.
// ---------------------------------------------------------------------------
#define OFF_FC 0
#define OFF_D0 32768
#define OFF_W0 294912
#define OFF_D1 425984
#define OFF_W1 491520
#define OFF_WS 557056
#define W_TOT  688128
__global__ __launch_bounds__(256) void cvt_all(const float* __restrict__ Wfc,
                                               const float* __restrict__ Wd0,
                                               const float* __restrict__ W0,
                                               const float* __restrict__ Wd1,
                                               const float* __restrict__ W1,
                                               const float* __restrict__ Wsc,
                                               half_t* __restrict__ w) {
    int i = blockIdx.x * 256 + threadIdx.x;
    if (i >= W_TOT) return;
    const float* src; int off;
    if (i < OFF_W0)      { if (i < OFF_D0) { src = Wfc; off = OFF_FC; }
                           else            { src = Wd0; off = OFF_D0; } }
    else if (i < OFF_W1) { if (i < OFF_D1) { src = W0;  off = OFF_W0; }
                           else            { src = Wd1; off = OFF_D1; } }
    else                 { if (i < OFF_WS) { src = W1;  off = OFF_W1; }
                           else            { src = Wsc; off = OFF_WS; } }
    w[i] = (half_t)src[i - off];
}

// ---------------------------------------------------------------------------
// Fused kNN + conv_pos: LDS point cloud, per-wave u32 butterfly selection
// (winners kept in LDS), then each lane computes the VN conv for 2 channels
// straight from the LDS cloud. idx never hits global. Output h1 fp16.
// ---------------------------------------------------------------------------
__global__ __launch_bounds__(256) void knn_conv(const float* __restrict__ x,
                                                const float* __restrict__ Wf,
                                                const float* __restrict__ Wd,
                                                half_t* __restrict__ h1) {
    __shared__ float xs[N_], ys[N_], zs[N_];
    __shared__ int opw[4][K_];
    int t = threadIdx.x;
    int wv = t >> 6, lane = t & 63;
    int b = blockIdx.x >> 8;
    int n = (blockIdx.x & 255) * 4 + wv;
    const float* xb = x + (size_t)b * N_ * 3;
    for (int j = t; j < N_; j += 256) {
        xs[j] = xb[j * 3 + 0];
        ys[j] = xb[j * 3 + 1];
        zs[j] = xb[j * 3 + 2];
    }
    __syncthreads();

    float cx = xs[n], cy = ys[n], cz = zs[n];
    uint ku[16];
    #pragma unroll
    for (int k = 0; k < 16; ++k) {
        int j = lane + (k << 6);
        float dx = xs[j] - cx, dy = ys[j] - cy, dz = zs[j] - cz;
        float d = dx * dx + dy * dy + dz * dz;
        ku[k] = (__float_as_uint(d) & 0xFFFFFC00u) | (uint)j;
    }
    for (int s = 0; s < K_; ++s) {
        uint m = ku[0];
        #pragma unroll
        for (int k = 1; k < 16; ++k) m = min(m, ku[k]);
        #pragma unroll
        for (int o = 32; o; o >>= 1) m = min(m, (uint)__shfl_xor((int)m, o));
        int j = (int)(m & 1023u);
        if ((j & 63) == lane) {
            opw[wv][s] = j;
            ku[j >> 6] = 0xFFFFFFFFu;
        }
    }
    __syncthreads();

    // conv for channels lane and lane+64
    float wf[2][3], wd[2][3];
    #pragma unroll
    for (int c = 0; c < 2; ++c) {
        int ch = lane + c * 64;
        wf[c][0] = Wf[ch * 3 + 0]; wf[c][1] = Wf[ch * 3 + 1]; wf[c][2] = Wf[ch * 3 + 2];
        wd[c][0] = Wd[ch * 3 + 0]; wd[c][1] = Wd[ch * 3 + 1]; wd[c][2] = Wd[ch * 3 + 2];
    }
    float ax[2] = {0.f, 0.f}, ay[2] = {0.f, 0.f}, az[2] = {0.f, 0.f};
    for (int k = 0; k < K_; ++k) {
        int j = opw[wv][k];
        float nx = xs[j], ny = ys[j], nz = zs[j];
        float ex = nx - cx, ey = ny - cy, ez = nz - cz;
        float rx = ny * cz - nz * cy;
        float ry = nz * cx - nx * cz;
        float rz = nx * cy - ny * cx;
        #pragma unroll
        for (int c = 0; c < 2; ++c) {
            float fx = wf[c][0] * ex + wf[c][1] * cx + wf[c][2] * rx;
            float fy = wf[c][0] * ey + wf[c][1] * cy + wf[c][2] * ry;
            float fz = wf[c][0] * ez + wf[c][1] * cz + wf[c][2] * rz;
            float gx = wd[c][0] * ex + wd[c][1] * cx + wd[c][2] * rx;
            float gy = wd[c][0] * ey + wd[c][1] * cy + wd[c][2] * ry;
            float gz = wd[c][0] * ez + wd[c][1] * cz + wd[c][2] * rz;
            float dot = fx * gx + fy * gy + fz * gz;
            float dsq = gx * gx + gy * gy + gz * gz + EPS_;
            float cf = dot / dsq;
            float qx, qy, qz;
            if (dot >= 0.f) { qx = fx; qy = fy; qz = fz; }
            else            { qx = fx - cf * gx; qy = fy - cf * gy; qz = fz - cf * gz; }
            ax[c] += 0.2f * fx + 0.8f * qx;
            ay[c] += 0.2f * fy + 0.8f * qy;
            az[c] += 0.2f * fz + 0.8f * qz;
        }
    }
    const float inv = 1.0f / (float)K_;
    size_t r0 = ((size_t)b * 3) * N_ + n;
    #pragma unroll
    for (int c = 0; c < 2; ++c) {
        int ch = lane + c * 64;
        h1[(r0) * H_ + ch]          = (half_t)(ax[c] * inv);
        h1[(r0 + N_) * H_ + ch]     = (half_t)(ay[c] * inv);
        h1[(r0 + 2 * N_) * H_ + ch] = (half_t)(az[c] * inv);
    }
}

// ---------------------------------------------------------------------------
// Swizzled LDS helpers (128/256-ch row buffers).
// ---------------------------------------------------------------------------
__device__ inline void stsw128(half_t* __restrict__ buf, int v, int n, int o, f4_t val) {
    int phys = (((o >> 3) ^ (n & 7)) * 8) + (o & 7);
    half_t* p = buf + (v * 16 + n) * 128 + phys;
    h4_t h;
    h[0] = (half_t)val[0]; h[1] = (half_t)val[1];
    h[2] = (half_t)val[2]; h[3] = (half_t)val[3];
    *(h4_t*)p = h;
}
__device__ inline f4_t ldsw128(const half_t* __restrict__ buf, int v, int n, int o) {
    int phys = (((o >> 3) ^ (n & 7)) * 8) + (o & 7);
    const half_t* p = buf + (v * 16 + n) * 128 + phys;
    h4_t x = *(const h4_t*)p;
    f4_t r;
    r[0] = (float)x[0]; r[1] = (float)x[1]; r[2] = (float)x[2]; r[3] = (float)x[3];
    return r;
}
__device__ inline void stsw256(half_t* __restrict__ buf, int v, int n, int o, f4_t val) {
    int phys = (((o >> 3) ^ (n & 7)) * 8) + (o & 7);
    half_t* p = buf + (v * 16 + n) * 256 + phys;
    h4_t h;
    h[0] = (half_t)val[0]; h[1] = (half_t)val[1];
    h[2] = (half_t)val[2]; h[3] = (half_t)val[3];
    *(h4_t*)p = h;
}
__device__ inline f4_t ldsw256(const half_t* __restrict__ buf, int v, int n, int o) {
    int phys = (((o >> 3) ^ (n & 7)) * 8) + (o & 7);
    const half_t* p = buf + (v * 16 + n) * 256 + phys;
    h4_t x = *(const h4_t*)p;
    f4_t r;
    r[0] = (float)x[0]; r[1] = (float)x[1]; r[2] = (float)x[2]; r[3] = (float)x[3];
    return r;
}

// ---------------------------------------------------------------------------
// block_full: entire resnet block per (n-tile 16, b) block. FIRST also
// computes Hd = Wfc * h1 into LDS (fc_pos fused).
// FIRST LDS (76 KB):  h1L/netL [0,12K) | HdL [12K,36K) | a0L/a1L [36K,60K)
//                     | As [60K,76K)
// non-FIRST (52 KB):  hL [0,12K) | a0L/As2 [12K,36K) incl a1L [24K,36K)
//                     | As1/netL [36K,52K)
// ---------------------------------------------------------------------------
template<bool FIRST, bool WRITE_OUT>
__global__ __launch_bounds__(256) void block_full(const half_t* __restrict__ Wfc,
                                                  const half_t* __restrict__ Wd0,
                                                  const half_t* __restrict__ W0,
                                                  const half_t* __restrict__ Wd1,
                                                  const half_t* __restrict__ Ws,
                                                  const half_t* __restrict__ W1,
                                                  const half_t* __restrict__ hprev,
                                                  const float* __restrict__ P,
                                                  const float* __restrict__ addD0,
                                                  const float* __restrict__ addWs,
                                                  half_t* __restrict__ outH,
                                                  float* __restrict__ Pp) {
    __shared__ __align__(16) char smem[FIRST ? 77824 : 53248];
    half_t* hL   = (half_t*)(smem);                              // h_prev / h1 tile
    half_t* netL = (half_t*)(FIRST ? smem : smem + 36864);
    half_t* HdL  = (half_t*)(smem + 12288);                      // FIRST only
    half_t* a0L  = (half_t*)(FIRST ? smem + 36864 : smem + 12288);
    half_t* a1L  = (half_t*)(FIRST ? smem + 36864 : smem + 24576);
    half_t* AsA  = (half_t*)(FIRST ? smem + 61440 : smem + 36864); // big staging
    half_t* AsB  = (half_t*)(FIRST ? smem + 61440 : smem + 12288); // S2/S3 staging

    const int t = threadIdx.x;
    const int lane = t & 63, wm = t >> 6;
    const int l16 = lane & 15, quad = lane >> 4;
    const int sw = (quad ^ (l16 & 3)) * 8;
    const int b  = blockIdx.z;
    const int nt = blockIdx.x;
    const int n0 = nt * 16;
    const size_t row0 = (size_t)(b * 3) * N_ + (n0 + l16);

    // ---- load hprev tile (h1 for FIRST, h for later) into hL ----
    #pragma unroll
    for (int c = t; c < 768; c += 256) {
        int v = c >> 8, rem = c & 255;
        int n = rem >> 4, ch = rem & 15;
        size_t g = (size_t)((b * 3 + v) * N_ + n0 + n) * 128 + ch * 8;
        *(uint4*)(hL + (v * 16 + n) * 128 + ((ch ^ (n & 7)) * 8)) =
            *(const uint4*)(hprev + g);
    }

    // ---- FIRST: Hd = Wfc(256x128) * h1 -> HdL ----
    if (FIRST) {
        f4_t facc[3][4];
        #pragma unroll
        for (int v = 0; v < 3; ++v)
            #pragma unroll
            for (int i = 0; i < 4; ++i)
                #pragma unroll
                for (int e = 0; e < 4; ++e) facc[v][i][e] = 0.f;
        for (int k0 = 0; k0 < 128; k0 += 32) {
            #pragma unroll
            for (int c = t; c < 1024; c += 256) {      // Wfc: 256 rows x 4 chunks
                int row = c >> 2, ch = c & 3;
                size_t g = (size_t)row * 128 + k0 + ch * 8;
                *(uint4*)(AsA + row * 32 + ((ch ^ (row & 3)) * 8)) =
                    *(const uint4*)(Wfc + g);
            }
            __syncthreads();
            h8_t ah[4], bh[3];
            #pragma unroll
            for (int i = 0; i < 4; ++i)
                ah[i] = *(const h8_t*)(AsA + (wm * 64 + i * 16 + l16) * 32 + sw);
            int lc = (k0 >> 3) + quad;
            #pragma unroll
            for (int v = 0; v < 3; ++v)
                bh[v] = *(const h8_t*)(hL + (v * 16 + l16) * 128 + ((lc ^ (l16 & 7)) * 8));
            #pragma unroll
            for (int v = 0; v < 3; ++v)
                #pragma unroll
                for (int i = 0; i < 4; ++i)
                    facc[v][i] = __builtin_amdgcn_mfma_f32_16x16x32_f16(
                        ah[i], bh[v], facc[v][i], 0, 0, 0);
            __syncthreads();
        }
        #pragma unroll
        for (int i = 0; i < 4; ++i) {
            int o = wm * 64 + i * 16 + quad * 4;
            #pragma unroll
            for (int v = 0; v < 3; ++v) stsw256(HdL, v, l16, o, facc[v][i]);
        }
    }

    // ------------- S0: a0 = vnrelu(hidden, Wd0*hidden(+addD0)) -------------
    {
        constexpr int C = FIRST ? 256 : 128;
        f4_t acc[3][4];
        #pragma unroll
        for (int v = 0; v < 3; ++v)
            #pragma unroll
            for (int i = 0; i < 4; ++i)
                #pragma unroll
                for (int e = 0; e < 4; ++e) acc[v][i][e] = 0.f;

        for (int k0 = 0; k0 < C; k0 += 32) {
            #pragma unroll
            for (int c = t; c < 1024; c += 256) {        // Wd0: 256 rows x 4 chunks
                int row = c >> 2, ch = c & 3;
                size_t g = (size_t)row * 256 + k0 + ch * 8;
                *(uint4*)(AsA + row * 32 + ((ch ^ (row & 3)) * 8)) =
                    *(const uint4*)(Wd0 + g);
            }
            __syncthreads();                              // orders HdL writes too
            h8_t ah[4], bh[3];
            #pragma unroll
            for (int i = 0; i < 4; ++i)
                ah[i] = *(const h8_t*)(AsA + (wm * 64 + i * 16 + l16) * 32 + sw);
            int lc = (k0 >> 3) + quad;
            if (FIRST) {
                #pragma unroll
                for (int v = 0; v < 3; ++v)
                    bh[v] = *(const h8_t*)(HdL + (v * 16 + l16) * 256 + ((lc ^ (l16 & 7)) * 8));
            } else {
                #pragma unroll
                for (int v = 0; v < 3; ++v)
                    bh[v] = *(const h8_t*)(hL + (v * 16 + l16) * 128 + ((lc ^ (l16 & 7)) * 8));
            }
            #pragma unroll
            for (int v = 0; v < 3; ++v)
                #pragma unroll
                for (int i = 0; i < 4; ++i)
                    acc[v][i] = __builtin_amdgcn_mfma_f32_16x16x32_f16(
                        ah[i], bh[v], acc[v][i], 0, 0, 0);
            __syncthreads();
        }
        #pragma unroll
        for (int i = 0; i < 4; ++i) {
            int o = wm * 64 + i * 16 + quad * 4;
            f4_t d[3], p[3];
            #pragma unroll
            for (int v = 0; v < 3; ++v) {
                d[v] = acc[v][i];
                if (!FIRST) {
                    float4 ra = *(const float4*)(addD0 + (size_t)(b * 3 + v) * 256 + o);
                    d[v][0] += ra.x; d[v][1] += ra.y; d[v][2] += ra.z; d[v][3] += ra.w;
                }
            }
            if (FIRST) {
                #pragma unroll
                for (int v = 0; v < 3; ++v)
                    p[v] = ldsw256(HdL, v, l16, o);
            } else {
                if (o < 128) {
                    #pragma unroll
                    for (int v = 0; v < 3; ++v)
                        p[v] = ldsw128(hL, v, l16, o);
                } else {
                    #pragma unroll
                    for (int e = 0; e < 4; ++e) {
                        const float* Pc = P + (size_t)(b * 128 + o - 128 + e) * 3;
                        p[0][e] = Pc[0]; p[1][e] = Pc[1]; p[2][e] = Pc[2];
                    }
                }
            }
            f4_t q[3];
            #pragma unroll
            for (int e = 0; e < 4; ++e) {
                float dot = p[0][e] * d[0][e] + p[1][e] * d[1][e] + p[2][e] * d[2][e];
                float dsq = d[0][e] * d[0][e] + d[1][e] * d[1][e] + d[2][e] * d[2][e] + EPS_;
                float cf = dot / dsq;
                if (dot >= 0.f) { q[0][e] = p[0][e]; q[1][e] = p[1][e]; q[2][e] = p[2][e]; }
                else {
                    q[0][e] = p[0][e] - cf * d[0][e];
                    q[1][e] = p[1][e] - cf * d[1][e];
                    q[2][e] = p[2][e] - cf * d[2][e];
                }
            }
            #pragma unroll
            for (int v = 0; v < 3; ++v) stsw256(a0L, v, l16, o, q[v]);
        }
    }

    // ------------- S1: net = W0 * a0 (C=256, a0 in LDS) -------------
    f4_t acc[3][2];
    #pragma unroll
    for (int v = 0; v < 3; ++v)
        #pragma unroll
        for (int i = 0; i < 2; ++i)
            #pragma unroll
            for (int e = 0; e < 4; ++e) acc[v][i][e] = 0.f;

    for (int k0 = 0; k0 < 256; k0 += 32) {
        #pragma unroll
        for (int c = t; c < 512; c += 256) {             // W0: 128 rows x 4 chunks
            int row = c >> 2, ch = c & 3;
            size_t g = (size_t)row * 256 + k0 + ch * 8;
            *(uint4*)(AsA + row * 32 + ((ch ^ (row & 3)) * 8)) = *(const uint4*)(W0 + g);
        }
        __syncthreads();                                 // orders a0L writes too
        h8_t ah[2], bh[3];
        #pragma unroll
        for (int i = 0; i < 2; ++i)
            ah[i] = *(const h8_t*)(AsA + (wm * 32 + i * 16 + l16) * 32 + sw);
        int lc = (k0 >> 3) + quad;
        #pragma unroll
        for (int v = 0; v < 3; ++v)
            bh[v] = *(const h8_t*)(a0L + (v * 16 + l16) * 256 + ((lc ^ (l16 & 7)) * 8));
        #pragma unroll
        for (int v = 0; v < 3; ++v)
            #pragma unroll
            for (int i = 0; i < 2; ++i)
                acc[v][i] = __builtin_amdgcn_mfma_f32_16x16x32_f16(
                    ah[i], bh[v], acc[v][i], 0, 0, 0);
        __syncthreads();
    }
    #pragma unroll
    for (int i = 0; i < 2; ++i) {
        int o = wm * 32 + i * 16 + quad * 4;
        #pragma unroll
        for (int v = 0; v < 3; ++v) stsw128(netL, v, l16, o, acc[v][i]);
    }

    // ------------- S2: a1 = vnrelu(net, Wd1*net) -------------
    #pragma unroll
    for (int v = 0; v < 3; ++v)
        #pragma unroll
        for (int i = 0; i < 2; ++i)
            #pragma unroll
            for (int e = 0; e < 4; ++e) acc[v][i][e] = 0.f;

    for (int k0 = 0; k0 < 128; k0 += 32) {
        #pragma unroll
        for (int c = t; c < 512; c += 256) {
            int row = c >> 2, ch = c & 3;
            size_t g = (size_t)row * 128 + k0 + ch * 8;
            *(uint4*)(AsB + row * 32 + ((ch ^ (row & 3)) * 8)) = *(const uint4*)(Wd1 + g);
        }
        __syncthreads();                                 // orders netL writes too
        h8_t ah[2], bh[3];
        #pragma unroll
        for (int i = 0; i < 2; ++i)
            ah[i] = *(const h8_t*)(AsB + (wm * 32 + i * 16 + l16) * 32 + sw);
        int lc = (k0 >> 3) + quad;
        #pragma unroll
        for (int v = 0; v < 3; ++v)
            bh[v] = *(const h8_t*)(netL + (v * 16 + l16) * 128 + ((lc ^ (l16 & 7)) * 8));
        #pragma unroll
        for (int v = 0; v < 3; ++v)
            #pragma unroll
            for (int i = 0; i < 2; ++i)
                acc[v][i] = __builtin_amdgcn_mfma_f32_16x16x32_f16(
                    ah[i], bh[v], acc[v][i], 0, 0, 0);
        __syncthreads();
    }
    #pragma unroll
    for (int i = 0; i < 2; ++i) {
        int o = wm * 32 + i * 16 + quad * 4;
        f4_t p[3], q[3];
        #pragma unroll
        for (int v = 0; v < 3; ++v) p[v] = ldsw128(netL, v, l16, o);
        #pragma unroll
        for (int e = 0; e < 4; ++e) {
            float dot = p[0][e] * acc[0][i][e] + p[1][e] * acc[1][i][e] + p[2][e] * acc[2][i][e];
            float dsq = acc[0][i][e] * acc[0][i][e] + acc[1][i][e] * acc[1][i][e]
                      + acc[2][i][e] * acc[2][i][e] + EPS_;
            float cf = dot / dsq;
            if (dot >= 0.f) { q[0][e] = p[0][e]; q[1][e] = p[1][e]; q[2][e] = p[2][e]; }
            else {
                q[0][e] = p[0][e] - cf * acc[0][i][e];
                q[1][e] = p[1][e] - cf * acc[1][i][e];
                q[2][e] = p[2][e] - cf * acc[2][i][e];
            }
        }
        #pragma unroll
        for (int v = 0; v < 3; ++v) stsw128(a1L, v, l16, o, q[v]);
    }
    __syncthreads();

    // ------------- S3: h = Ws*hidden + W1*a1 (+addWs) -------------
    #pragma unroll
    for (int v = 0; v < 3; ++v)
        #pragma unroll
        for (int i = 0; i < 2; ++i)
            #pragma unroll
            for (int e = 0; e < 4; ++e) acc[v][i][e] = 0.f;

    {
        constexpr int C0 = FIRST ? 256 : 128;
        for (int k0 = 0; k0 < C0; k0 += 32) {            // segment 0: Ws * hidden
            #pragma unroll
            for (int c = t; c < 512; c += 256) {
                int row = c >> 2, ch = c & 3;
                size_t g = (size_t)row * 256 + k0 + ch * 8;   // Ws lda = 256
                *(uint4*)(AsB + row * 32 + ((ch ^ (row & 3)) * 8)) = *(const uint4*)(Ws + g);
            }
            __syncthreads();
            h8_t ah[2], bh[3];
            #pragma unroll
            for (int i = 0; i < 2; ++i)
                ah[i] = *(const h8_t*)(AsB + (wm * 32 + i * 16 + l16) * 32 + sw);
            int lc = (k0 >> 3) + quad;
            if (FIRST) {
                #pragma unroll
                for (int v = 0; v < 3; ++v)
                    bh[v] = *(const h8_t*)(HdL + (v * 16 + l16) * 256 + ((lc ^ (l16 & 7)) * 8));
            } else {
                #pragma unroll
                for (int v = 0; v < 3; ++v)
                    bh[v] = *(const h8_t*)(hL + (v * 16 + l16) * 128 + ((lc ^ (l16 & 7)) * 8));
            }
            #pragma unroll
            for (int v = 0; v < 3; ++v)
                #pragma unroll
                for (int i = 0; i < 2; ++i)
                    acc[v][i] = __builtin_amdgcn_mfma_f32_16x16x32_f16(
                        ah[i], bh[v], acc[v][i], 0, 0, 0);
            __syncthreads();
        }
        for (int k0 = 0; k0 < 128; k0 += 32) {           // segment 1: W1 * a1 (LDS)
            #pragma unroll
            for (int c = t; c < 512; c += 256) {
                int row = c >> 2, ch = c & 3;
                size_t g = (size_t)row * 128 + k0 + ch * 8;
                *(uint4*)(AsB + row * 32 + ((ch ^ (row & 3)) * 8)) = *(const uint4*)(W1 + g);
            }
            __syncthreads();
            h8_t ah[2], bh[3];
            #pragma unroll
            for (int i = 0; i < 2; ++i)
                ah[i] = *(const h8_t*)(AsB + (wm * 32 + i * 16 + l16) * 32 + sw);
            int lc = (k0 >> 3) + quad;
            #pragma unroll
            for (int v = 0; v < 3; ++v)
                bh[v] = *(const h8_t*)(a1L + (v * 16 + l16) * 128 + ((lc ^ (l16 & 7)) * 8));
            #pragma unroll
            for (int v = 0; v < 3; ++v)
                #pragma unroll
                for (int i = 0; i < 2; ++i)
                    acc[v][i] = __builtin_amdgcn_mfma_f32_16x16x32_f16(
                        ah[i], bh[v], acc[v][i], 0, 0, 0);
            __syncthreads();
        }
    }

    const size_t slot = (size_t)b * 64 + nt;
    #pragma unroll
    for (int i = 0; i < 2; ++i) {
        int o = wm * 32 + i * 16 + quad * 4;
        f4_t d[3];
        #pragma unroll
        for (int v = 0; v < 3; ++v) {
            d[v] = acc[v][i];
            if (!FIRST) {
                float4 ra = *(const float4*)(addWs + (size_t)(b * 3 + v) * 128 + o);
                d[v][0] += ra.x; d[v][1] += ra.y; d[v][2] += ra.z; d[v][3] += ra.w;
            }
            if (WRITE_OUT)
                st4h(outH, (row0 + (size_t)v * N_) * 128 + o, d[v]);
        }
        #pragma unroll
        for (int v = 0; v < 3; ++v)
            #pragma unroll
            for (int e = 0; e < 4; ++e) {
                float s = d[v][e];
                s += __shfl_xor(s, 1);
                s += __shfl_xor(s, 2);
                s += __shfl_xor(s, 4);
                s += __shfl_xor(s, 8);
                d[v][e] = s;
            }
        if (l16 == 0) {
            #pragma unroll
            for (int v = 0; v < 3; ++v)
                #pragma unroll
                for (int e = 0; e < 4; ++e)
                    Pp[slot * 384 + (size_t)(o + e) * 3 + v] = d[v][e];
        }
    }
}

// ---------------------------------------------------------------------------
// Fused pool stage 2 + (optional) rowadd for the NEXT block.
// ---------------------------------------------------------------------------
template<bool ROWADD>
__global__ __launch_bounds__(256) void pool_rowadd(const float* __restrict__ Pp,
                                                   const float* __restrict__ Wd0n,
                                                   const float* __restrict__ Wsn,
                                                   float* __restrict__ P,
                                                   float* __restrict__ addD0,
                                                   float* __restrict__ addWs) {
    int s = blockIdx.x;
    int b = s / 3, v = s % 3;
    int t = threadIdx.x;
    __shared__ float Pl[128];
    if (t < 128) {
        float sum = 0.f;
        const float* p = Pp + (size_t)b * 64 * 384 + (size_t)t * 3 + v;
        #pragma unroll 4
        for (int sl = 0; sl < 64; ++sl) sum += p[(size_t)sl * 384];
        sum *= (1.0f / (float)N_);
        Pl[t] = sum;
        P[(size_t)(b * 128 + t) * 3 + v] = sum;
    }
    __syncthreads();
    if (ROWADD) {
        float sum = 0.f;
        const float* wr = Wd0n + (size_t)t * 256 + 128;
        #pragma unroll 8
        for (int c = 0; c < 128; ++c) sum += wr[c] * Pl[c];
        addD0[(size_t)s * 256 + t] = sum;
        if (t < 128) {
            const float* wr2 = Wsn + (size_t)t * 256 + 128;
            float s2 = 0.f;
            #pragma unroll 8
            for (int c = 0; c < 128; ++c) s2 += wr2[c] * Pl[c];
            addWs[(size_t)s * 128 + t] = s2;
        }
    }
}

// ---------------------------------------------------------------------------
// Final stage (fp32, exact)
// ---------------------------------------------------------------------------
__global__ __launch_bounds__(128) void final_kernel(const float* __restrict__ P,
                                                    const float* __restrict__ Wd,
                                                    const float* __restrict__ Wc,
                                                    float* __restrict__ out) {
    int b = blockIdx.x;
    int t = threadIdx.x;
    __shared__ float hid[H_][3];
    __shared__ float act[H_][3];
    const float* Pb = P + (size_t)b * H_ * 3;
    hid[t][0] = Pb[t * 3 + 0];
    hid[t][1] = Pb[t * 3 + 1];
    hid[t][2] = Pb[t * 3 + 2];
    __syncthreads();

    float d0 = 0.f, d1 = 0.f, d2 = 0.f;
    const float* wd = Wd + (size_t)t * H_;
    for (int c = 0; c < H_; ++c) {
        float w = wd[c];
        d0 += w * hid[c][0]; d1 += w * hid[c][1]; d2 += w * hid[c][2];
    }
    float p0 = hid[t][0], p1 = hid[t][1], p2 = hid[t][2];
    float dot = p0 * d0 + p1 * d1 + p2 * d2;
    float dsq = d0 * d0 + d1 * d1 + d2 * d2 + EPS_;
    float cf = dot / dsq;
    float q0, q1, q2;
    if (dot >= 0.f) { q0 = p0; q1 = p1; q2 = p2; }
    else            { q0 = p0 - cf * d0; q1 = p1 - cf * d1; q2 = p2 - cf * d2; }
    act[t][0] = 0.2f * p0 + 0.8f * q0;
    act[t][1] = 0.2f * p1 + 0.8f * q1;
    act[t][2] = 0.2f * p2 + 0.8f * q2;
    __syncthreads();

    float o0 = 0.f, o1 = 0.f, o2 = 0.f;
    const float* wc = Wc + (size_t)t * H_;
    for (int c = 0; c < H_; ++c) {
        float w = wc[c];
        o0 += w * act[c][0]; o1 += w * act[c][1]; o2 += w * act[c][2];
    }
    size_t ob = ((size_t)b * H_ + t) * 3;
    out[ob + 0] = o0; out[ob + 1] = o1; out[ob + 2] = o2;
}

// ---------------------------------------------------------------------------
extern "C" void kernel_launch(void* const* d_in, const int* in_sizes, int n_in,
                              void* d_out, int out_size, void* d_ws, size_t ws_size,
                              hipStream_t stream) {
    const float* x   = (const float*)d_in[0];
    const float* Wf  = (const float*)d_in[1];
    const float* Wdp = (const float*)d_in[2];
    const float* Wfc = (const float*)d_in[3];
    const float* Wd0 = (const float*)d_in[4];
    const float* W0  = (const float*)d_in[5];
    const float* Wd1 = (const float*)d_in[6];
    const float* W1  = (const float*)d_in[7];
    const float* Wsc = (const float*)d_in[8];
    const float* Wda = (const float*)d_in[9];
    const float* Wc  = (const float*)d_in[10];
    float* out = (float*)d_out;
    (void)in_sizes; (void)n_in; (void)out_size; (void)ws_size;

    char* ws = (char*)d_ws;
    size_t off = 0;
    auto alloc = [&](size_t bytes) {
        void* p = ws + off;
        off = (off + bytes + 255) & ~(size_t)255;
        return p;
    };
    const size_t e128 = (size_t)R_ * 128;
    half_t* wAll  = (half_t*)alloc((size_t)W_TOT * 2);
    half_t* h1F   = (half_t*)alloc(e128 * 2);
    half_t* hF[2] = { (half_t*)alloc(e128 * 2), (half_t*)alloc(e128 * 2) };
    float*  addD0 = (float*) alloc(24 * 256 * 4);
    float*  addWs = (float*) alloc(24 * 128 * 4);
    float*  Pp    = (float*) alloc((size_t)B_ * 64 * 384 * 4);
    float*  P     = (float*) alloc((size_t)B_ * 128 * 3 * 4);

    const half_t* whFc = wAll + OFF_FC;
    const half_t* whD0 = wAll + OFF_D0;
    const half_t* whW0 = wAll + OFF_W0;
    const half_t* whD1 = wAll + OFF_D1;
    const half_t* whW1 = wAll + OFF_W1;
    const half_t* whWs = wAll + OFF_WS;

    hipLaunchKernelGGL(cvt_all, dim3((W_TOT + 255) / 256), dim3(256), 0, stream,
                       Wfc, Wd0, W0, Wd1, W1, Wsc, wAll);
    hipLaunchKernelGGL(knn_conv, dim3(B_ * N_ / 4), dim3(256), 0, stream,
                       x, Wf, Wdp, h1F);

    for (int i = 0; i < 4; ++i) {
        int cur = i & 1, prv = cur ^ 1;
        if (i == 0) {
            block_full<true, true><<<dim3(64, 1, 8), 256, 0, stream>>>(
                whFc, whD0, whW0, whD1, whWs, whW1,
                h1F, nullptr, nullptr, nullptr, hF[cur], Pp);
        } else if (i < 3) {
            block_full<false, true><<<dim3(64, 1, 8), 256, 0, stream>>>(
                whFc, whD0 + (size_t)i * 65536, whW0 + (size_t)i * 32768,
                whD1 + (size_t)i * 16384, whWs + (size_t)i * 32768,
                whW1 + (size_t)i * 16384,
                hF[prv], P, addD0, addWs, hF[cur], Pp);
        } else {
            block_full<false, false><<<dim3(64, 1, 8), 256, 0, stream>>>(
                whFc, whD0 + (size_t)i * 65536, whW0 + (size_t)i * 32768,
                whD1 + (size_t)i * 16384, whWs + (size_t)i * 32768,
                whW1 + (size_t)i * 16384,
                hF[prv], P, addD0, addWs, nullptr, Pp);
        }
        if (i < 3) {
            hipLaunchKernelGGL((pool_rowadd<true>), dim3(24), dim3(256), 0, stream,
                               Pp, Wd0 + (size_t)(i + 1) * 65536,
                               Wsc + (size_t)(i + 1) * 32768, P, addD0, addWs);
        } else {
            hipLaunchKernelGGL((pool_rowadd<false>), dim3(24), dim3(256), 0, stream,
                               Pp, nullptr, nullptr, P, nullptr, nullptr);
        }
    }

    hipLaunchKernelGGL(final_kernel, dim3(B_), dim3(128), 0, stream, P, Wda, Wc, out);
}